// Round 10
// baseline (435.021 us; speedup 1.0000x reference)
//
#include <hip/hip_runtime.h>
#include <hip/hip_bf16.h>
#include <math.h>

typedef __hip_bfloat16 bf16;
typedef __attribute__((ext_vector_type(8))) short short8;
typedef __attribute__((ext_vector_type(4))) float floatx4;

static constexpr int TOK = 32768;
static constexpr int CDIM = 384;
static constexpr int HID = 1536;

__device__ __forceinline__ bf16 f2bf(float v) { return __float2bfloat16(v); }

__device__ __forceinline__ unsigned short bf_bits(float a) {
  bf16 h = __float2bfloat16(a);
  unsigned short u;
  __builtin_memcpy(&u, &h, 2);
  return u;
}
__device__ __forceinline__ unsigned pack2(float a, float b) {
  return (unsigned)bf_bits(a) | ((unsigned)bf_bits(b) << 16);
}

typedef const __attribute__((address_space(1))) unsigned gas_t;
typedef __attribute__((address_space(3))) unsigned las_t;
__device__ __forceinline__ void gload16(const bf16* g, const bf16* l) {
  __builtin_amdgcn_global_load_lds((gas_t*)g, (las_t*)l, 16, 0, 0);
}

// ---------------- all 4 weight conversions fused into one launch ------------
__global__ __launch_bounds__(256) void k_convt4(
    const float* __restrict__ s0, bf16* __restrict__ d0,
    const float* __restrict__ s1, bf16* __restrict__ d1,
    const float* __restrict__ s2, bf16* __restrict__ d2,
    const float* __restrict__ s3, bf16* __restrict__ d3) {
  int tid = blockIdx.x * 256 + threadIdx.x;
  const float* src; bf16* dst; int Kd, Nd, off;
  if (tid < 442368) { src = s0; dst = d0; Kd = 384; Nd = 1152; off = tid; }
  else if (tid < 589824) { src = s1; dst = d1; Kd = 384; Nd = 384; off = tid - 442368; }
  else if (tid < 1179648) { src = s2; dst = d2; Kd = 384; Nd = 1536; off = tid - 589824; }
  else { src = s3; dst = d3; Kd = 1536; Nd = 384; off = tid - 1179648; }
  int k = off / Nd, n = off - k * Nd;
  dst[(size_t)n * Kd + k] = f2bf(src[off]);
}

// ---------------- LN1 + shift + window partition (4 tokens/block) -----------
__global__ __launch_bounds__(256) void k_ln1(const float* __restrict__ x,
                                             const float* __restrict__ g,
                                             const float* __restrict__ b,
                                             bf16* __restrict__ out) {
  int wt = blockIdx.x * 4 + (threadIdx.x >> 6);
  int lane = threadIdx.x & 63;
  int win = wt >> 6, ntok = wt & 63;
  int bimg = win >> 4, wi = win & 15;
  int sh = (((wi >> 2) << 3) + (ntok >> 3) + 4) & 31;
  int sw = (((wi & 3) << 3) + (ntok & 7) + 4) & 31;
  const float* xr = x + ((size_t)bimg * 1024 + sh * 32 + sw) * CDIM;
  float v[6]; float s = 0.f, ss = 0.f;
#pragma unroll
  for (int j = 0; j < 6; ++j) {
    float t = xr[j * 64 + lane];
    v[j] = t; s += t; ss += t * t;
  }
#pragma unroll
  for (int off = 32; off > 0; off >>= 1) {
    s += __shfl_xor(s, off, 64);
    ss += __shfl_xor(ss, off, 64);
  }
  float mu = s * (1.f / 384.f);
  float var = ss * (1.f / 384.f) - mu * mu;
  float rs = rsqrtf(var + 1e-5f);
  bf16* orow = out + (size_t)wt * CDIM;
#pragma unroll
  for (int j = 0; j < 6; ++j) {
    int c = j * 64 + lane;
    orow[c] = f2bf((v[j] - mu) * rs * g[c] + b[c]);
  }
}

// ---------------- LN2 (normal token order, 4 tokens/block) ------------------
__global__ __launch_bounds__(256) void k_ln2(const float* __restrict__ x1,
                                             const float* __restrict__ g,
                                             const float* __restrict__ b,
                                             bf16* __restrict__ out) {
  int t = blockIdx.x * 4 + (threadIdx.x >> 6);
  int lane = threadIdx.x & 63;
  const float* xr = x1 + (size_t)t * CDIM;
  float v[6]; float s = 0.f, ss = 0.f;
#pragma unroll
  for (int j = 0; j < 6; ++j) {
    float q = xr[j * 64 + lane];
    v[j] = q; s += q; ss += q * q;
  }
#pragma unroll
  for (int off = 32; off > 0; off >>= 1) {
    s += __shfl_xor(s, off, 64);
    ss += __shfl_xor(ss, off, 64);
  }
  float mu = s * (1.f / 384.f);
  float var = ss * (1.f / 384.f) - mu * mu;
  float rs = rsqrtf(var + 1e-5f);
  bf16* orow = out + (size_t)t * CDIM;
#pragma unroll
  for (int j = 0; j < 6; ++j) {
    int c = j * 64 + lane;
    orow[c] = f2bf((v[j] - mu) * rs * g[c] + b[c]);
  }
}

// ============ GEMM: 128x128 tile, 3x BK=32 buffers, depth-2 counted vmcnt ===
// (round-2 proven config: 256 threads, 48 KiB LDS, vmcnt(4))
template <int K, int EPI, int NT>
__global__ __launch_bounds__(256) void k_gemm(const bf16* __restrict__ A,
                                              const bf16* __restrict__ Bt,
                                              const float* __restrict__ bias,
                                              const float* __restrict__ extra,
                                              void* __restrict__ outp) {
  __shared__ __attribute__((aligned(16))) char pool[49152];
  bf16* A0 = (bf16*)pool;
  bf16* B0 = (bf16*)(pool + 8192);
  bf16* A1 = (bf16*)(pool + 16384);
  bf16* B1 = (bf16*)(pool + 24576);
  bf16* A2 = (bf16*)(pool + 32768);
  bf16* B2 = (bf16*)(pool + 40960);

  const int tid = threadIdx.x;
  const int wv = tid >> 6, lane = tid & 63;

  const int flat = blockIdx.x;
  const int xcd = flat & 7;
  const int idx = flat >> 3;
  const int rpx = (gridDim.x >> 3) / NT;
  const int cb = idx % NT;
  const int rb = idx / NT;
  const int mblk = (xcd * rpx + rb) * 128, nblk = cb * 128;

  const int srow = lane >> 3;
  const int sc = (lane & 7) ^ srow;
  const int srow2 = 2 * srow + (sc >> 2);
  const int gco = (sc & 3) * 8;
  const bf16* gaw = A + (size_t)(mblk + wv * 32 + srow2) * K + gco;
  const bf16* gbw = Bt + (size_t)(nblk + wv * 32 + srow2) * K + gco;
  bf16* lA0 = A0 + wv * 1024; bf16* lB0 = B0 + wv * 1024;
  bf16* lA1 = A1 + wv * 1024; bf16* lB1 = B1 + wv * 1024;
  bf16* lA2 = A2 + wv * 1024; bf16* lB2 = B2 + wv * 1024;

  const int wr = wv >> 1, wc = wv & 1;
  const int mr = lane & 15, q = lane >> 4;
  const int slot8 = ((((mr & 1) << 2) | q) ^ (mr >> 1)) * 8;
  const int faOff = (wr * 32 + (mr >> 1)) * 64 + slot8;
  const int fbOff = (wc * 32 + (mr >> 1)) * 64 + slot8;

  floatx4 acc[4][4];
#pragma unroll
  for (int i = 0; i < 4; ++i)
#pragma unroll
    for (int j = 0; j < 4; ++j) acc[i][j] = floatx4{0.f, 0.f, 0.f, 0.f};

#define VM4() asm volatile("s_waitcnt vmcnt(4)" ::: "memory")
#define VM0() asm volatile("s_waitcnt vmcnt(0)" ::: "memory")
#define BAR() __builtin_amdgcn_s_barrier()

#define STAGE(LA, LB, KOFF) do { \
    gload16(gaw + (KOFF), (LA)); \
    gload16(gaw + (KOFF) + 16 * K, (LA) + 512); \
    gload16(gbw + (KOFF), (LB)); \
    gload16(gbw + (KOFF) + 16 * K, (LB) + 512); \
  } while (0)

#define COMPUTE(ABASE, BBASE) do { \
    short8 a_[4], b_[4]; \
    _Pragma("unroll") \
    for (int mt = 0; mt < 4; ++mt) a_[mt] = *(const short8*)((ABASE) + faOff + mt * 512); \
    _Pragma("unroll") \
    for (int nt = 0; nt < 4; ++nt) b_[nt] = *(const short8*)((BBASE) + fbOff + nt * 512); \
    _Pragma("unroll") \
    for (int mt = 0; mt < 4; ++mt) \
      _Pragma("unroll") \
      for (int nt = 0; nt < 4; ++nt) \
        acc[mt][nt] = __builtin_amdgcn_mfma_f32_16x16x32_bf16(a_[mt], b_[nt], acc[mt][nt], 0, 0, 0); \
  } while (0)

  STAGE(lA0, lB0, 0);
  STAGE(lA1, lB1, 32);
  for (int k0 = 0; k0 < K - 96; k0 += 96) {
    VM4(); BAR(); STAGE(lA2, lB2, k0 + 64);  COMPUTE(A0, B0);
    VM4(); BAR(); STAGE(lA0, lB0, k0 + 96);  COMPUTE(A1, B1);
    VM4(); BAR(); STAGE(lA1, lB1, k0 + 128); COMPUTE(A2, B2);
  }
  VM4(); BAR(); STAGE(lA2, lB2, K - 32); COMPUTE(A0, B0);
  VM4(); BAR();                          COMPUTE(A1, B1);
  VM0(); BAR();                          COMPUTE(A2, B2);
#undef STAGE
#undef COMPUTE
#undef VM4
#undef VM0
#undef BAR

  __syncthreads();
  float* epsw = (float*)pool + wv * (16 * 68);
  const int rr = lane >> 2, c0 = (lane & 3) * 16;
#pragma unroll
  for (int mt = 0; mt < 4; ++mt) {
#pragma unroll
    for (int nt = 0; nt < 4; ++nt)
#pragma unroll
      for (int r = 0; r < 4; ++r)
        epsw[(q * 4 + r) * 68 + nt * 16 + mr] = acc[mt][nt][r];
    float v[16];
#pragma unroll
    for (int j = 0; j < 4; ++j) {
      float4 t = *(const float4*)&epsw[rr * 68 + c0 + j * 4];
      v[j * 4 + 0] = t.x; v[j * 4 + 1] = t.y; v[j * 4 + 2] = t.z; v[j * 4 + 3] = t.w;
    }
    const int grow = mblk + wr * 64 + mt * 16 + rr;
    const int gcol = nblk + wc * 64 + c0;

    if constexpr (EPI == 0) {
      int win = grow >> 6, ntok = grow & 63;
      int s = gcol / 384;
      int rem = gcol - s * 384;
      int h = rem >> 5, d0 = rem & 31;
      bf16* op = (bf16*)outp + (((size_t)s * 512 + win) * 12 + h) * 2048 + ntok * 32 + d0;
      uint4 pk;
      float bv[16];
#pragma unroll
      for (int j = 0; j < 16; ++j) bv[j] = v[j] + bias[gcol + j];
      pk.x = pack2(bv[0], bv[1]); pk.y = pack2(bv[2], bv[3]);
      pk.z = pack2(bv[4], bv[5]); pk.w = pack2(bv[6], bv[7]);
      *(uint4*)op = pk;
      pk.x = pack2(bv[8], bv[9]); pk.y = pack2(bv[10], bv[11]);
      pk.z = pack2(bv[12], bv[13]); pk.w = pack2(bv[14], bv[15]);
      *(uint4*)(op + 8) = pk;
    } else if constexpr (EPI == 1) {
      int win = grow >> 6, ntok = grow & 63;
      int bimg = win >> 4, wi = win & 15;
      int hh = (((wi >> 2) << 3) + (ntok >> 3) + 4) & 31;
      int ww = (((wi & 3) << 3) + (ntok & 7) + 4) & 31;
      size_t t = (size_t)bimg * 1024 + hh * 32 + ww;
      float* op = (float*)outp + t * CDIM + gcol;
      const float* xr = extra + t * CDIM + gcol;
#pragma unroll
      for (int j = 0; j < 4; ++j) {
        float4 xv = *(const float4*)(xr + j * 4);
        float4 ov;
        ov.x = xv.x + v[j * 4 + 0] + bias[gcol + j * 4 + 0];
        ov.y = xv.y + v[j * 4 + 1] + bias[gcol + j * 4 + 1];
        ov.z = xv.z + v[j * 4 + 2] + bias[gcol + j * 4 + 2];
        ov.w = xv.w + v[j * 4 + 3] + bias[gcol + j * 4 + 3];
        *(float4*)(op + j * 4) = ov;
      }
    }
  }
}

// ===================== fused MLP: x1 + fc2(gelu(fc1(ln2))) ==================
// v3: (a) GEMM1 at BK=64 double-buffered -> 6 steps + 7 barriers per chunk
// (was 12 steps + 19); (b) W2 fragments loaded DIRECT global->reg from L2
// (derivation: old LDS path's bytes == W2t[(wc1*96+nt*16+mr)*1536 + ci*128
// + kk*32 + q*8]), so GEMM2 is barrier-free and waves drift -> one wave's
// L2 latency hides under another's MFMA.  LDS 96 KiB: A dbuf 32K | W1 dbuf
// 32K | h 32K.  vmcnt: step0=2 (drain prev-step ST, keep b1), steps1-5=0
// (each drains a 1-step-old ST; ~full-step cover).
__global__ __launch_bounds__(512, 2) void k_mlp(const bf16* __restrict__ A,
                                                const bf16* __restrict__ W1t,
                                                const bf16* __restrict__ W2t,
                                                const float* __restrict__ b1,
                                                const float* __restrict__ b2,
                                                const float* __restrict__ x1,
                                                float* __restrict__ out) {
  __shared__ __attribute__((aligned(16))) char pool[98304];
  bf16* A0 = (bf16*)pool;               // 16 KiB = two 8 KiB k-halves
  bf16* A1 = (bf16*)(pool + 16384);
  bf16* W10 = (bf16*)(pool + 32768);
  bf16* W11 = (bf16*)(pool + 49152);
  bf16* hs = (bf16*)(pool + 65536);     // [128 tok][16 slots][8], XOR layout

  const int tid = threadIdx.x;
  const int wv = tid >> 6, lane = tid & 63;
  const int mblk = blockIdx.x * 128;

  const int srow = lane >> 3;
  const int sc = (lane & 7) ^ srow;
  const int srow2 = 2 * srow + (sc >> 2);
  const int gco = (sc & 3) * 8;

  const bf16* ga = A + (size_t)(mblk + wv * 16 + srow2) * 384 + gco;
  const bf16* g1 = W1t + (size_t)(wv * 16 + srow2) * 384 + gco;

  const int wr1 = wv >> 2, wc1 = wv & 3;
  const int mr = lane & 15, q = lane >> 4;
  const int slot8 = ((((mr & 1) << 2) | q) ^ (mr >> 1)) * 8;
  const int faOff1 = (wr1 * 32 + (mr >> 1)) * 64 + slot8;
  const int fbOff1 = (wc1 * 16 + (mr >> 1)) * 64 + slot8;
  const size_t hb = (size_t)(wr1 * 64 + mr) * 128;
  // direct W2 B-fragment source (bit-identical to old LDS path):
  //   wb[nt] = 16B @ W2t[(wc1*96 + nt*16 + mr)*1536 + ci*128 + kk*32 + q*8]
  const bf16* gW2 = W2t + (size_t)(wc1 * 96 + mr) * 1536 + q * 8;
  int px[4];
#pragma unroll
  for (int kk = 0; kk < 4; ++kk)
    px[kk] = (((kk & 2) << 2) | ((((kk & 1) << 2) | q) ^ (mr & 7))) * 8;

  floatx4 acc1[4][2];
  floatx4 acc2[4][6];
#pragma unroll
  for (int i = 0; i < 4; ++i) {
#pragma unroll
    for (int j = 0; j < 2; ++j) acc1[i][j] = floatx4{0.f, 0.f, 0.f, 0.f};
#pragma unroll
    for (int j = 0; j < 6; ++j) acc2[i][j] = floatx4{0.f, 0.f, 0.f, 0.f};
  }

#define VMW(N) asm volatile("s_waitcnt vmcnt(" #N ")" ::: "memory")
#define LGKM0() asm volatile("s_waitcnt lgkmcnt(0)" ::: "memory")
#define BARR() __builtin_amdgcn_s_barrier()
// stage BK=64 tile: two 8 KiB k-halves of A and of W1 (4 gloads/wave)
#define ST(ABUF, WBUF, G1P, KO) do { \
    gload16(ga + (KO), (ABUF) + wv * 512); \
    gload16(ga + (KO) + 32, (ABUF) + 4096 + wv * 512); \
    gload16((G1P) + (KO), (WBUF) + wv * 512); \
    gload16((G1P) + (KO) + 32, (WBUF) + 4096 + wv * 512); \
  } while (0)
// BK=64 compute: two k-halves, frags scoped per half (pressure control)
#define C1X(AB, WB) do { \
    _Pragma("unroll") \
    for (int kk = 0; kk < 2; ++kk) { \
      short8 a_[4], b_[2]; \
      _Pragma("unroll") \
      for (int mt = 0; mt < 4; ++mt) \
        a_[mt] = *(const short8*)((AB) + kk * 4096 + faOff1 + mt * 512); \
      b_[0] = *(const short8*)((WB) + kk * 4096 + fbOff1); \
      b_[1] = *(const short8*)((WB) + kk * 4096 + fbOff1 + 512); \
      _Pragma("unroll") \
      for (int mt = 0; mt < 4; ++mt) \
        _Pragma("unroll") \
        for (int nt = 0; nt < 2; ++nt) \
          acc1[mt][nt] = __builtin_amdgcn_mfma_f32_16x16x32_bf16(a_[mt], b_[nt], acc1[mt][nt], 0, 0, 0); \
    } \
  } while (0)
// GEMM2 slice: h from LDS, W2 direct from global (L2-resident)
#define C2D(GW2C, KK) do { \
    short8 ha[4], wb[6]; \
    _Pragma("unroll") \
    for (int mt = 0; mt < 4; ++mt) \
      ha[mt] = *(const short8*)(hs + hb + mt * 2048 + px[KK]); \
    _Pragma("unroll") \
    for (int nt = 0; nt < 6; ++nt) \
      wb[nt] = *(const short8*)((GW2C) + (size_t)nt * 24576 + (KK) * 32); \
    _Pragma("unroll") \
    for (int mt = 0; mt < 4; ++mt) \
      _Pragma("unroll") \
      for (int nt = 0; nt < 6; ++nt) \
        acc2[mt][nt] = __builtin_amdgcn_mfma_f32_16x16x32_bf16(ha[mt], wb[nt], acc2[mt][nt], 0, 0, 0); \
  } while (0)
// GELU + bias -> h (XOR layout), rezero acc1
#define GELU_H(BB0, BB1) do { \
    _Pragma("unroll") \
    for (int mt = 0; mt < 4; ++mt) { \
      const int tokb = wr1 * 64 + mt * 16 + q * 4; \
      _Pragma("unroll") \
      for (int nt = 0; nt < 2; ++nt) { \
        const float bb = nt ? (BB1) : (BB0); \
        const int sw = wc1 * 4 + nt * 2 + (mr >> 3); \
        const int s8 = sw & 8, s7 = sw & 7; \
        _Pragma("unroll") \
        for (int r = 0; r < 4; ++r) { \
          float z = acc1[mt][nt][r] + bb; \
          float t2 = z * z; \
          float cp = __builtin_fmaf(t2, -0.0713548162f, -1.5957691216f); \
          float e = __expf(z * cp); \
          float gl = z * __builtin_amdgcn_rcpf(1.f + e); \
          const int t7 = ((q & 1) << 2) | r; \
          hs[(size_t)(tokb + r) * 128 + (s8 | (s7 ^ t7)) * 8 + (mr & 7)] = f2bf(gl); \
        } \
        acc1[mt][nt] = floatx4{0.f, 0.f, 0.f, 0.f}; \
      } \
    } \
    LGKM0(); \
  } while (0)

  // prologue: stage chunk 0's first BK=64 tile
  ST(A0, W10, g1, 0);

  for (int ci = 0; ci < 12; ++ci) {
    float bb0 = b1[ci * 128 + wc1 * 32 + mr];
    float bb1 = b1[ci * 128 + wc1 * 32 + 16 + mr];
    const bf16* g1n = g1 + 49152;
    const bf16* gW2c = gW2 + ci * 128;

    VMW(2); BARR(); ST(A1, W11, g1, 64);   C1X(A0, W10);
    VMW(0); BARR(); ST(A0, W10, g1, 128);  C1X(A1, W11);
    VMW(0); BARR(); ST(A1, W11, g1, 192);  C1X(A0, W10);
    VMW(0); BARR(); ST(A0, W10, g1, 256);  C1X(A1, W11);
    VMW(0); BARR(); ST(A1, W11, g1, 320);  C1X(A0, W10);
    VMW(0); BARR(); ST(A0, W10, g1n, 0);   C1X(A1, W11);

    GELU_H(bb0, bb1);
    __syncthreads();

    // ---- GEMM2: barrier-free; W2 direct from L2, h from LDS ----
    C2D(gW2c, 0);
    C2D(gW2c, 1);
    C2D(gW2c, 2);
    C2D(gW2c, 3);

    g1 += 49152;
  }
#undef ST
#undef C1X
#undef C2D
#undef GELU_H

  VMW(0);           // drain last stray stage (lands in A0/W10, never read)
  __syncthreads();  // before epsw aliases the A/W1 region

  // ---- epilogue: out = x1 + acc2 + b2 ----
  float* epsw = (float*)(pool + wv * 6400);  // [16][100] f32 per wave
  const int rr = lane >> 2, c4 = (lane & 3) * 24;
#pragma unroll
  for (int mt = 0; mt < 4; ++mt) {
#pragma unroll
    for (int nt = 0; nt < 6; ++nt)
#pragma unroll
      for (int r = 0; r < 4; ++r)
        epsw[(q * 4 + r) * 100 + nt * 16 + mr] = acc2[mt][nt][r];
    const int grow = mblk + wr1 * 64 + mt * 16 + rr;
    const int gcol = wc1 * 96 + c4;
    const float* xr = x1 + (size_t)grow * 384 + gcol;
    float* op = out + (size_t)grow * 384 + gcol;
#pragma unroll
    for (int j = 0; j < 6; ++j) {
      float4 t = *(const float4*)&epsw[rr * 100 + c4 + j * 4];
      float4 xv = *(const float4*)(xr + j * 4);
      float4 bv = *(const float4*)&b2[gcol + j * 4];
      float4 ov;
      ov.x = xv.x + t.x + bv.x;
      ov.y = xv.y + t.y + bv.y;
      ov.z = xv.z + t.z + bv.z;
      ov.w = xv.w + t.w + bv.w;
      *(float4*)(op + j * 4) = ov;
    }
  }
#undef VMW
#undef LGKM0
#undef BARR
}

// ============ attention on MFMA: 1 wave per (window, head) ==================
__global__ __launch_bounds__(64) void k_attn(const bf16* __restrict__ qkv,
                                             const float* __restrict__ tblg,
                                             bf16* __restrict__ out) {
  __shared__ __attribute__((aligned(16))) char pool[16384];
  bf16* Qs = (bf16*)pool;                                   // [64][40]
  bf16* Ks = (bf16*)(pool + 5120);                          // [64][40]
  bf16* Ps = (bf16*)pool;                                   // [64][72] alias
  float* Os = (float*)pool;                                 // [64][40] alias
  bf16* Vt = (bf16*)(pool + 10240);                         // [32][72]
  unsigned long long* msk = (unsigned long long*)(pool + 14848);  // [64]
  float* tbl = (float*)(pool + 15360);                      // [225]

  const int bid = blockIdx.x;
  const int win = bid / 12, head = bid - win * 12;
  const int lane = threadIdx.x;
  const int q = lane >> 4, mr = lane & 15;

  for (int i = lane; i < 225; i += 64) tbl[i] = tblg[i * 12 + head];

  size_t base = ((size_t)win * 12 + head) * 2048 + lane * 32;
  const uint4* qp = (const uint4*)(qkv + base);
  const uint4* kp = (const uint4*)(qkv + (size_t)12582912 + base);
  const uint4* vp = (const uint4*)(qkv + (size_t)25165824 + base);
#pragma unroll
  for (int i = 0; i < 4; ++i) *(uint4*)(Qs + lane * 40 + i * 8) = qp[i];
#pragma unroll
  for (int i = 0; i < 4; ++i) *(uint4*)(Ks + lane * 40 + i * 8) = kp[i];
  {
    union { uint4 u[4]; unsigned short h[32]; } vv;
#pragma unroll
    for (int i = 0; i < 4; ++i) vv.u[i] = vp[i];
    unsigned short* VtU = (unsigned short*)Vt;
#pragma unroll
    for (int d = 0; d < 32; ++d) VtU[d * 72 + lane] = vv.h[d];
  }
  {
    int wi = win & 15;
    int ri = lane >> 3, ci = lane & 7;
    int rh = ((wi >> 2) << 3) + ri, rw = ((wi & 3) << 3) + ci;
    int rid = (rh < 24 ? 0 : (rh < 28 ? 1 : 2)) * 3 + (rw < 24 ? 0 : (rw < 28 ? 1 : 2));
    unsigned long long m = 0;
#pragma unroll
    for (int v = 0; v < 9; ++v) {
      unsigned long long bb = __ballot(rid == v);
      if (rid == v) m = bb;
    }
    msk[lane] = m;
  }
  // single wave: LDS ops execute in program order, no barrier needed

  // ---- S = Q.K^T ----
  floatx4 sac[4][4];
#pragma unroll
  for (int i = 0; i < 4; ++i)
#pragma unroll
    for (int j = 0; j < 4; ++j) sac[i][j] = floatx4{0.f, 0.f, 0.f, 0.f};
  {
    short8 af[4], bf[4];
#pragma unroll
    for (int t = 0; t < 4; ++t) af[t] = *(const short8*)(Qs + (t * 16 + mr) * 40 + q * 8);
#pragma unroll
    for (int t = 0; t < 4; ++t) bf[t] = *(const short8*)(Ks + (t * 16 + mr) * 40 + q * 8);
    __builtin_amdgcn_s_setprio(1);
#pragma unroll
    for (int mt = 0; mt < 4; ++mt)
#pragma unroll
      for (int nt = 0; nt < 4; ++nt)
        sac[mt][nt] = __builtin_amdgcn_mfma_f32_16x16x32_bf16(af[mt], bf[nt], sac[mt][nt], 0, 0, 0);
    __builtin_amdgcn_s_setprio(0);
  }

  // ---- epilogue: scale + bias + mask + exp; row sums; P -> LDS bf16 ----
  float psum[4][4];
#pragma unroll
  for (int mt = 0; mt < 4; ++mt)
#pragma unroll
    for (int r = 0; r < 4; ++r) psum[mt][r] = 0.f;
#pragma unroll
  for (int mt = 0; mt < 4; ++mt) {
#pragma unroll
    for (int r = 0; r < 4; ++r) {
      const int i = mt * 16 + q * 4 + r;
      const unsigned long long mrow = msk[i];
      const int bi = (i >> 3) * 15 + (i & 7);
#pragma unroll
      for (int nt = 0; nt < 4; ++nt) {
        const int j = nt * 16 + mr;
        const int idx = bi + 112 - (j >> 3) * 15 - (j & 7);
        float val = sac[mt][nt][r] * 0.17677669529663687f + tbl[idx];
        float p = __expf(val);
        p = ((mrow >> j) & 1ull) ? p : 0.f;
        psum[mt][r] += p;
        Ps[i * 72 + j] = f2bf(p);
      }
    }
  }
  float inv[4][4];
#pragma unroll
  for (int mt = 0; mt < 4; ++mt)
#pragma unroll
    for (int r = 0; r < 4; ++r) {
      float s = psum[mt][r];
      s += __shfl_xor(s, 1, 64);
      s += __shfl_xor(s, 2, 64);
      s += __shfl_xor(s, 4, 64);
      s += __shfl_xor(s, 8, 64);
      inv[mt][r] = 1.f / s;
    }

  // ---- O = P.V ----
  floatx4 oac[4][2];
#pragma unroll
  for (int i = 0; i < 4; ++i)
#pragma unroll
    for (int j = 0; j < 2; ++j) oac[i][j] = floatx4{0.f, 0.f, 0.f, 0.f};
#pragma unroll
  for (int kk = 0; kk < 2; ++kk) {
    short8 ap[4], bv[2];
#pragma unroll
    for (int mt = 0; mt < 4; ++mt)
      ap[mt] = *(const short8*)(Ps + (mt * 16 + mr) * 72 + kk * 32 + q * 8);
#pragma unroll
    for (int nt = 0; nt < 2; ++nt)
      bv[nt] = *(const short8*)(Vt + (nt * 16 + mr) * 72 + kk * 32 + q * 8);
    __builtin_amdgcn_s_setprio(1);
#pragma unroll
    for (int mt = 0; mt < 4; ++mt)
#pragma unroll
      for (int nt = 0; nt < 2; ++nt)
        oac[mt][nt] = __builtin_amdgcn_mfma_f32_16x16x32_bf16(ap[mt], bv[nt], oac[mt][nt], 0, 0, 0);
    __builtin_amdgcn_s_setprio(0);
  }

  // ---- normalize + LDS round-trip -> vectorized store ----
#pragma unroll
  for (int mt = 0; mt < 4; ++mt)
#pragma unroll
    for (int nt = 0; nt < 2; ++nt)
#pragma unroll
      for (int r = 0; r < 4; ++r)
        Os[(mt * 16 + q * 4 + r) * 40 + nt * 16 + mr] = oac[mt][nt][r] * inv[mt][r];
  float ov[32];
#pragma unroll
  for (int c = 0; c < 8; ++c) {
    const int cc = c ^ (lane & 7);
    float4 t = *(const float4*)(Os + lane * 40 + cc * 4);
    ov[cc * 4 + 0] = t.x; ov[cc * 4 + 1] = t.y;
    ov[cc * 4 + 2] = t.z; ov[cc * 4 + 3] = t.w;
  }
  uint4* o4 = (uint4*)(out + ((size_t)win * 64 + lane) * CDIM + head * 32);
#pragma unroll
  for (int i = 0; i < 4; ++i) {
    uint4 pk;
    pk.x = pack2(ov[i * 8 + 0], ov[i * 8 + 1]);
    pk.y = pack2(ov[i * 8 + 2], ov[i * 8 + 3]);
    pk.z = pack2(ov[i * 8 + 4], ov[i * 8 + 5]);
    pk.w = pack2(ov[i * 8 + 6], ov[i * 8 + 7]);
    o4[i] = pk;
  }
}

extern "C" void kernel_launch(void* const* d_in, const int* in_sizes, int n_in,
                              void* d_out, int out_size, void* d_ws, size_t ws_size,
                              hipStream_t stream) {
  const float* x = (const float*)d_in[0];
  const float* n1g = (const float*)d_in[1];
  const float* n1b = (const float*)d_in[2];
  const float* qkv_w = (const float*)d_in[3];
  const float* qkv_b = (const float*)d_in[4];
  const float* reltbl = (const float*)d_in[5];
  const float* proj_w = (const float*)d_in[6];
  const float* proj_b = (const float*)d_in[7];
  const float* n2g = (const float*)d_in[8];
  const float* n2b = (const float*)d_in[9];
  const float* fc1_w = (const float*)d_in[10];
  const float* fc1_b = (const float*)d_in[11];
  const float* fc2_w = (const float*)d_in[12];
  const float* fc2_b = (const float*)d_in[13];
  float* out = (float*)d_out;

  char* p = (char*)d_ws;
  bf16* w_qkv_t = (bf16*)p;  p += (size_t)442368 * 2;
  bf16* w_proj_t = (bf16*)p; p += (size_t)147456 * 2;
  bf16* w_fc1_t = (bf16*)p;  p += (size_t)589824 * 2;
  bf16* w_fc2_t = (bf16*)p;  p += (size_t)589824 * 2;
  bf16* bufA = (bf16*)p;     p += (size_t)12582912 * 2;
  bf16* qkvb = (bf16*)p;     p += (size_t)37748736 * 2;
  bf16* attno = (bf16*)p;    p += (size_t)12582912 * 2;
  float* x1 = (float*)p;     p += (size_t)12582912 * 4;

  k_convt4<<<dim3(6912), dim3(256), 0, stream>>>(qkv_w, w_qkv_t, proj_w, w_proj_t,
                                                 fc1_w, w_fc1_t, fc2_w, w_fc2_t);

  k_ln1<<<dim3(8192), dim3(256), 0, stream>>>(x, n1g, n1b, bufA);
  k_gemm<384, 0, 9><<<dim3(9 * 256), dim3(256), 0, stream>>>(bufA, w_qkv_t, qkv_b, nullptr, qkvb);
  k_attn<<<dim3(6144), dim3(64), 0, stream>>>(qkvb, reltbl, attno);
  k_gemm<384, 1, 3><<<dim3(3 * 256), dim3(256), 0, stream>>>(attno, w_proj_t, proj_b, x, x1);
  k_ln2<<<dim3(8192), dim3(256), 0, stream>>>(x1, n2g, n2b, bufA);
  k_mlp<<<dim3(256), dim3(512), 0, stream>>>(bufA, w_fc1_t, w_fc2_t, fc1_b, fc2_b, x1, out);
}

// Round 11
// 400.501 us; speedup vs baseline: 1.0862x; 1.0862x over previous
//
#include <hip/hip_runtime.h>
#include <hip/hip_bf16.h>
#include <math.h>

typedef __hip_bfloat16 bf16;
typedef __attribute__((ext_vector_type(8))) short short8;
typedef __attribute__((ext_vector_type(4))) float floatx4;

static constexpr int TOK = 32768;
static constexpr int CDIM = 384;
static constexpr int HID = 1536;

__device__ __forceinline__ bf16 f2bf(float v) { return __float2bfloat16(v); }

__device__ __forceinline__ unsigned short bf_bits(float a) {
  bf16 h = __float2bfloat16(a);
  unsigned short u;
  __builtin_memcpy(&u, &h, 2);
  return u;
}
__device__ __forceinline__ unsigned pack2(float a, float b) {
  return (unsigned)bf_bits(a) | ((unsigned)bf_bits(b) << 16);
}

typedef const __attribute__((address_space(1))) unsigned gas_t;
typedef __attribute__((address_space(3))) unsigned las_t;
__device__ __forceinline__ void gload16(const bf16* g, const bf16* l) {
  __builtin_amdgcn_global_load_lds((gas_t*)g, (las_t*)l, 16, 0, 0);
}

// ---------------- all 4 weight conversions fused into one launch ------------
__global__ __launch_bounds__(256) void k_convt4(
    const float* __restrict__ s0, bf16* __restrict__ d0,
    const float* __restrict__ s1, bf16* __restrict__ d1,
    const float* __restrict__ s2, bf16* __restrict__ d2,
    const float* __restrict__ s3, bf16* __restrict__ d3) {
  int tid = blockIdx.x * 256 + threadIdx.x;
  const float* src; bf16* dst; int Kd, Nd, off;
  if (tid < 442368) { src = s0; dst = d0; Kd = 384; Nd = 1152; off = tid; }
  else if (tid < 589824) { src = s1; dst = d1; Kd = 384; Nd = 384; off = tid - 442368; }
  else if (tid < 1179648) { src = s2; dst = d2; Kd = 384; Nd = 1536; off = tid - 589824; }
  else { src = s3; dst = d3; Kd = 1536; Nd = 384; off = tid - 1179648; }
  int k = off / Nd, n = off - k * Nd;
  dst[(size_t)n * Kd + k] = f2bf(src[off]);
}

// ---------------- LN1 + shift + window partition (4 tokens/block) -----------
__global__ __launch_bounds__(256) void k_ln1(const float* __restrict__ x,
                                             const float* __restrict__ g,
                                             const float* __restrict__ b,
                                             bf16* __restrict__ out) {
  int wt = blockIdx.x * 4 + (threadIdx.x >> 6);
  int lane = threadIdx.x & 63;
  int win = wt >> 6, ntok = wt & 63;
  int bimg = win >> 4, wi = win & 15;
  int sh = (((wi >> 2) << 3) + (ntok >> 3) + 4) & 31;
  int sw = (((wi & 3) << 3) + (ntok & 7) + 4) & 31;
  const float* xr = x + ((size_t)bimg * 1024 + sh * 32 + sw) * CDIM;
  float v[6]; float s = 0.f, ss = 0.f;
#pragma unroll
  for (int j = 0; j < 6; ++j) {
    float t = xr[j * 64 + lane];
    v[j] = t; s += t; ss += t * t;
  }
#pragma unroll
  for (int off = 32; off > 0; off >>= 1) {
    s += __shfl_xor(s, off, 64);
    ss += __shfl_xor(ss, off, 64);
  }
  float mu = s * (1.f / 384.f);
  float var = ss * (1.f / 384.f) - mu * mu;
  float rs = rsqrtf(var + 1e-5f);
  bf16* orow = out + (size_t)wt * CDIM;
#pragma unroll
  for (int j = 0; j < 6; ++j) {
    int c = j * 64 + lane;
    orow[c] = f2bf((v[j] - mu) * rs * g[c] + b[c]);
  }
}

// ---------------- LN2 (normal token order, 4 tokens/block) ------------------
__global__ __launch_bounds__(256) void k_ln2(const float* __restrict__ x1,
                                             const float* __restrict__ g,
                                             const float* __restrict__ b,
                                             bf16* __restrict__ out) {
  int t = blockIdx.x * 4 + (threadIdx.x >> 6);
  int lane = threadIdx.x & 63;
  const float* xr = x1 + (size_t)t * CDIM;
  float v[6]; float s = 0.f, ss = 0.f;
#pragma unroll
  for (int j = 0; j < 6; ++j) {
    float q = xr[j * 64 + lane];
    v[j] = q; s += q; ss += q * q;
  }
#pragma unroll
  for (int off = 32; off > 0; off >>= 1) {
    s += __shfl_xor(s, off, 64);
    ss += __shfl_xor(ss, off, 64);
  }
  float mu = s * (1.f / 384.f);
  float var = ss * (1.f / 384.f) - mu * mu;
  float rs = rsqrtf(var + 1e-5f);
  bf16* orow = out + (size_t)t * CDIM;
#pragma unroll
  for (int j = 0; j < 6; ++j) {
    int c = j * 64 + lane;
    orow[c] = f2bf((v[j] - mu) * rs * g[c] + b[c]);
  }
}

// ============ GEMM: 128x128 tile, 3x BK=32 buffers, depth-2 counted vmcnt ===
// (round-2 proven config: 256 threads, 48 KiB LDS, vmcnt(4))
template <int K, int EPI, int NT>
__global__ __launch_bounds__(256) void k_gemm(const bf16* __restrict__ A,
                                              const bf16* __restrict__ Bt,
                                              const float* __restrict__ bias,
                                              const float* __restrict__ extra,
                                              void* __restrict__ outp) {
  __shared__ __attribute__((aligned(16))) char pool[49152];
  bf16* A0 = (bf16*)pool;
  bf16* B0 = (bf16*)(pool + 8192);
  bf16* A1 = (bf16*)(pool + 16384);
  bf16* B1 = (bf16*)(pool + 24576);
  bf16* A2 = (bf16*)(pool + 32768);
  bf16* B2 = (bf16*)(pool + 40960);

  const int tid = threadIdx.x;
  const int wv = tid >> 6, lane = tid & 63;

  const int flat = blockIdx.x;
  const int xcd = flat & 7;
  const int idx = flat >> 3;
  const int rpx = (gridDim.x >> 3) / NT;
  const int cb = idx % NT;
  const int rb = idx / NT;
  const int mblk = (xcd * rpx + rb) * 128, nblk = cb * 128;

  const int srow = lane >> 3;
  const int sc = (lane & 7) ^ srow;
  const int srow2 = 2 * srow + (sc >> 2);
  const int gco = (sc & 3) * 8;
  const bf16* gaw = A + (size_t)(mblk + wv * 32 + srow2) * K + gco;
  const bf16* gbw = Bt + (size_t)(nblk + wv * 32 + srow2) * K + gco;
  bf16* lA0 = A0 + wv * 1024; bf16* lB0 = B0 + wv * 1024;
  bf16* lA1 = A1 + wv * 1024; bf16* lB1 = B1 + wv * 1024;
  bf16* lA2 = A2 + wv * 1024; bf16* lB2 = B2 + wv * 1024;

  const int wr = wv >> 1, wc = wv & 1;
  const int mr = lane & 15, q = lane >> 4;
  const int slot8 = ((((mr & 1) << 2) | q) ^ (mr >> 1)) * 8;
  const int faOff = (wr * 32 + (mr >> 1)) * 64 + slot8;
  const int fbOff = (wc * 32 + (mr >> 1)) * 64 + slot8;

  floatx4 acc[4][4];
#pragma unroll
  for (int i = 0; i < 4; ++i)
#pragma unroll
    for (int j = 0; j < 4; ++j) acc[i][j] = floatx4{0.f, 0.f, 0.f, 0.f};

#define VM4() asm volatile("s_waitcnt vmcnt(4)" ::: "memory")
#define VM0() asm volatile("s_waitcnt vmcnt(0)" ::: "memory")
#define BAR() __builtin_amdgcn_s_barrier()

#define STAGE(LA, LB, KOFF) do { \
    gload16(gaw + (KOFF), (LA)); \
    gload16(gaw + (KOFF) + 16 * K, (LA) + 512); \
    gload16(gbw + (KOFF), (LB)); \
    gload16(gbw + (KOFF) + 16 * K, (LB) + 512); \
  } while (0)

#define COMPUTE(ABASE, BBASE) do { \
    short8 a_[4], b_[4]; \
    _Pragma("unroll") \
    for (int mt = 0; mt < 4; ++mt) a_[mt] = *(const short8*)((ABASE) + faOff + mt * 512); \
    _Pragma("unroll") \
    for (int nt = 0; nt < 4; ++nt) b_[nt] = *(const short8*)((BBASE) + fbOff + nt * 512); \
    _Pragma("unroll") \
    for (int mt = 0; mt < 4; ++mt) \
      _Pragma("unroll") \
      for (int nt = 0; nt < 4; ++nt) \
        acc[mt][nt] = __builtin_amdgcn_mfma_f32_16x16x32_bf16(a_[mt], b_[nt], acc[mt][nt], 0, 0, 0); \
  } while (0)

  STAGE(lA0, lB0, 0);
  STAGE(lA1, lB1, 32);
  for (int k0 = 0; k0 < K - 96; k0 += 96) {
    VM4(); BAR(); STAGE(lA2, lB2, k0 + 64);  COMPUTE(A0, B0);
    VM4(); BAR(); STAGE(lA0, lB0, k0 + 96);  COMPUTE(A1, B1);
    VM4(); BAR(); STAGE(lA1, lB1, k0 + 128); COMPUTE(A2, B2);
  }
  VM4(); BAR(); STAGE(lA2, lB2, K - 32); COMPUTE(A0, B0);
  VM4(); BAR();                          COMPUTE(A1, B1);
  VM0(); BAR();                          COMPUTE(A2, B2);
#undef STAGE
#undef COMPUTE
#undef VM4
#undef VM0
#undef BAR

  __syncthreads();
  float* epsw = (float*)pool + wv * (16 * 68);
  const int rr = lane >> 2, c0 = (lane & 3) * 16;
#pragma unroll
  for (int mt = 0; mt < 4; ++mt) {
#pragma unroll
    for (int nt = 0; nt < 4; ++nt)
#pragma unroll
      for (int r = 0; r < 4; ++r)
        epsw[(q * 4 + r) * 68 + nt * 16 + mr] = acc[mt][nt][r];
    float v[16];
#pragma unroll
    for (int j = 0; j < 4; ++j) {
      float4 t = *(const float4*)&epsw[rr * 68 + c0 + j * 4];
      v[j * 4 + 0] = t.x; v[j * 4 + 1] = t.y; v[j * 4 + 2] = t.z; v[j * 4 + 3] = t.w;
    }
    const int grow = mblk + wr * 64 + mt * 16 + rr;
    const int gcol = nblk + wc * 64 + c0;

    if constexpr (EPI == 0) {
      int win = grow >> 6, ntok = grow & 63;
      int s = gcol / 384;
      int rem = gcol - s * 384;
      int h = rem >> 5, d0 = rem & 31;
      bf16* op = (bf16*)outp + (((size_t)s * 512 + win) * 12 + h) * 2048 + ntok * 32 + d0;
      uint4 pk;
      float bv[16];
#pragma unroll
      for (int j = 0; j < 16; ++j) bv[j] = v[j] + bias[gcol + j];
      pk.x = pack2(bv[0], bv[1]); pk.y = pack2(bv[2], bv[3]);
      pk.z = pack2(bv[4], bv[5]); pk.w = pack2(bv[6], bv[7]);
      *(uint4*)op = pk;
      pk.x = pack2(bv[8], bv[9]); pk.y = pack2(bv[10], bv[11]);
      pk.z = pack2(bv[12], bv[13]); pk.w = pack2(bv[14], bv[15]);
      *(uint4*)(op + 8) = pk;
    } else if constexpr (EPI == 1) {
      int win = grow >> 6, ntok = grow & 63;
      int bimg = win >> 4, wi = win & 15;
      int hh = (((wi >> 2) << 3) + (ntok >> 3) + 4) & 31;
      int ww = (((wi & 3) << 3) + (ntok & 7) + 4) & 31;
      size_t t = (size_t)bimg * 1024 + hh * 32 + ww;
      float* op = (float*)outp + t * CDIM + gcol;
      const float* xr = extra + t * CDIM + gcol;
#pragma unroll
      for (int j = 0; j < 4; ++j) {
        float4 xv = *(const float4*)(xr + j * 4);
        float4 ov;
        ov.x = xv.x + v[j * 4 + 0] + bias[gcol + j * 4 + 0];
        ov.y = xv.y + v[j * 4 + 1] + bias[gcol + j * 4 + 1];
        ov.z = xv.z + v[j * 4 + 2] + bias[gcol + j * 4 + 2];
        ov.w = xv.w + v[j * 4 + 3] + bias[gcol + j * 4 + 3];
        *(float4*)(op + j * 4) = ov;
      }
    }
  }
}

// ===================== fused MLP: x1 + fc2(gelu(fc1(ln2))) ==================
// v2 pipelined schedule (HW-verified correct in round 7) with the REAL fix:
// __launch_bounds__(512, 1).  Grid is 256 = exactly 1 block/CU, so the old
// (512,2) declaration only capped VGPR at 128 and forced the interleave to
// spill (round-7: WRITE_SIZE +22MB).  (512,1) -> 256-VGPR budget, no spill.
// Schedule: GEMM2(ci-1)'s C2 slices ride at steps 1/3/5/7 of GEMM1(ci);
// W2 slices stage at steps 2/4 (s2,s3 of ci-1) and 6/8 (s0,s1 of ci).
// 13 barriers/chunk; every segment carries independent C1+C2 work.
__global__ __launch_bounds__(512, 1) void k_mlp(const bf16* __restrict__ A,
                                                const bf16* __restrict__ W1t,
                                                const bf16* __restrict__ W2t,
                                                const float* __restrict__ b1,
                                                const float* __restrict__ b2,
                                                const float* __restrict__ x1,
                                                float* __restrict__ out) {
  __shared__ __attribute__((aligned(16))) char pool[131072];
  bf16* A0 = (bf16*)pool;
  bf16* A1 = (bf16*)(pool + 8192);
  bf16* A2 = (bf16*)(pool + 16384);
  bf16* W10 = (bf16*)(pool + 24576);
  bf16* W11 = (bf16*)(pool + 32768);
  bf16* W12 = (bf16*)(pool + 40960);
  bf16* hs = (bf16*)(pool + 49152);     // [128 tok][16 slots][8], XOR layout
  bf16* W2sA = (bf16*)(pool + 81920);   // [192 rowpair][64] = 24 KiB
  bf16* W2sB = (bf16*)(pool + 106496);  // [192 rowpair][64] = 24 KiB

  const int tid = threadIdx.x;
  const int wv = tid >> 6, lane = tid & 63;
  const int mblk = blockIdx.x * 128;

  const int srow = lane >> 3;
  const int sc = (lane & 7) ^ srow;
  const int srow2 = 2 * srow + (sc >> 2);
  const int gco = (sc & 3) * 8;

  const bf16* ga = A + (size_t)(mblk + wv * 16 + srow2) * 384 + gco;
  const bf16* g1 = W1t + (size_t)(wv * 16 + srow2) * 384 + gco;
  const bf16* g2 = W2t + (size_t)(wv * 48 + srow2) * 1536 + gco;

  const int wr1 = wv >> 2, wc1 = wv & 3;
  const int mr = lane & 15, q = lane >> 4;
  const int slot8 = ((((mr & 1) << 2) | q) ^ (mr >> 1)) * 8;
  const int faOff1 = (wr1 * 32 + (mr >> 1)) * 64 + slot8;
  const int fbOff1 = (wc1 * 16 + (mr >> 1)) * 64 + slot8;
  const int fbOff2 = (wc1 * 48 + (mr >> 1)) * 64 + slot8;
  const size_t hb = (size_t)(wr1 * 64 + mr) * 128;
  int px[4];
#pragma unroll
  for (int kk = 0; kk < 4; ++kk)
    px[kk] = (((kk & 2) << 2) | ((((kk & 1) << 2) | q) ^ (mr & 7))) * 8;

  floatx4 acc1[4][2];
  floatx4 acc2[4][6];
#pragma unroll
  for (int i = 0; i < 4; ++i) {
#pragma unroll
    for (int j = 0; j < 2; ++j) acc1[i][j] = floatx4{0.f, 0.f, 0.f, 0.f};
#pragma unroll
    for (int j = 0; j < 6; ++j) acc2[i][j] = floatx4{0.f, 0.f, 0.f, 0.f};
  }

#define VMW(N) asm volatile("s_waitcnt vmcnt(" #N ")" ::: "memory")
#define LGKM0() asm volatile("s_waitcnt lgkmcnt(0)" ::: "memory")
#define BARR() __builtin_amdgcn_s_barrier()
#define ST(ABUF, WBUF, G1P, KO) do { \
    gload16(ga + (KO), (ABUF) + wv * 512); \
    gload16((G1P) + (KO), (WBUF) + wv * 512); \
  } while (0)
#define STW2(BUF, KK, G2P) do { \
    _Pragma("unroll") \
    for (int g = 0; g < 3; ++g) \
      gload16((G2P) + (KK) * 32 + (size_t)g * 16 * 1536, (BUF) + wv * 1536 + g * 512); \
  } while (0)
#define C1(AB, WB) do { \
    short8 a_[4], b_[2]; \
    _Pragma("unroll") \
    for (int mt = 0; mt < 4; ++mt) a_[mt] = *(const short8*)((AB) + faOff1 + mt * 512); \
    b_[0] = *(const short8*)((WB) + fbOff1); \
    b_[1] = *(const short8*)((WB) + fbOff1 + 512); \
    _Pragma("unroll") \
    for (int mt = 0; mt < 4; ++mt) \
      _Pragma("unroll") \
      for (int nt = 0; nt < 2; ++nt) \
        acc1[mt][nt] = __builtin_amdgcn_mfma_f32_16x16x32_bf16(a_[mt], b_[nt], acc1[mt][nt], 0, 0, 0); \
  } while (0)
#define C2(BUF, KK) do { \
    short8 ha[4], wb[6]; \
    _Pragma("unroll") \
    for (int mt = 0; mt < 4; ++mt) \
      ha[mt] = *(const short8*)(hs + hb + mt * 2048 + px[KK]); \
    _Pragma("unroll") \
    for (int nt = 0; nt < 6; ++nt) \
      wb[nt] = *(const short8*)((BUF) + fbOff2 + nt * 512); \
    _Pragma("unroll") \
    for (int mt = 0; mt < 4; ++mt) \
      _Pragma("unroll") \
      for (int nt = 0; nt < 6; ++nt) \
        acc2[mt][nt] = __builtin_amdgcn_mfma_f32_16x16x32_bf16(ha[mt], wb[nt], acc2[mt][nt], 0, 0, 0); \
  } while (0)
// GELU + bias -> h (XOR layout), rezero acc1
#define GELU_H(BB0, BB1) do { \
    _Pragma("unroll") \
    for (int mt = 0; mt < 4; ++mt) { \
      const int tokb = wr1 * 64 + mt * 16 + q * 4; \
      _Pragma("unroll") \
      for (int nt = 0; nt < 2; ++nt) { \
        const float bb = nt ? (BB1) : (BB0); \
        const int sw = wc1 * 4 + nt * 2 + (mr >> 3); \
        const int s8 = sw & 8, s7 = sw & 7; \
        _Pragma("unroll") \
        for (int r = 0; r < 4; ++r) { \
          float z = acc1[mt][nt][r] + bb; \
          float t2 = z * z; \
          float cp = __builtin_fmaf(t2, -0.0713548162f, -1.5957691216f); \
          float e = __expf(z * cp); \
          float gl = z * __builtin_amdgcn_rcpf(1.f + e); \
          const int t7 = ((q & 1) << 2) | r; \
          hs[(size_t)(tokb + r) * 128 + (s8 | (s7 ^ t7)) * 8 + (mr & 7)] = f2bf(gl); \
        } \
        acc1[mt][nt] = floatx4{0.f, 0.f, 0.f, 0.f}; \
      } \
    } \
    LGKM0(); \
  } while (0)

  // ---- chunk 0 peel (GEMM1 only; stage W2(0) s0,s1 at steps 6,8) ----
  {
    float bb0 = b1[wc1 * 32 + mr];
    float bb1 = b1[wc1 * 32 + 16 + mr];
    ST(A0, W10, g1, 0);
    ST(A1, W11, g1, 32);
    const bf16* g1n = g1 + 49152;
    VMW(2); BARR(); ST(A2, W12, g1, 64);                       C1(A0, W10);
    VMW(2); BARR(); ST(A0, W10, g1, 96);                       C1(A1, W11);
    VMW(2); BARR(); ST(A1, W11, g1, 128);                      C1(A2, W12);
    VMW(2); BARR(); ST(A2, W12, g1, 160);                      C1(A0, W10);
    VMW(2); BARR(); ST(A0, W10, g1, 192);                      C1(A1, W11);
    VMW(2); BARR(); ST(A1, W11, g1, 224);                      C1(A2, W12);
    VMW(2); BARR(); ST(A2, W12, g1, 256); STW2(W2sA, 0, g2);   C1(A0, W10);
    VMW(5); BARR(); ST(A0, W10, g1, 288);                      C1(A1, W11);
    VMW(5); BARR(); ST(A1, W11, g1, 320); STW2(W2sB, 1, g2);   C1(A2, W12);
    VMW(5); BARR(); ST(A2, W12, g1, 352);                      C1(A0, W10);
    VMW(5); BARR(); ST(A0, W10, g1n, 0);                       C1(A1, W11);
    VMW(2); BARR(); ST(A1, W11, g1n, 32);                      C1(A2, W12);
    GELU_H(bb0, bb1);
    g1 += 49152;
  }

  // ---- steady chunks 1..11: GEMM1(ci) with C2(ci-1) interleaved ----
  for (int ci = 1; ci < 12; ++ci) {
    float bb0 = b1[ci * 128 + wc1 * 32 + mr];
    float bb1 = b1[ci * 128 + wc1 * 32 + 16 + mr];
    const bf16* g1n = g1 + 49152;
    const bf16* g2n = g2 + 128;
    VMW(4); BARR(); ST(A2, W12, g1, 64);                        C1(A0, W10);
    VMW(4); BARR(); ST(A0, W10, g1, 96);                        C1(A1, W11); C2(W2sA, 0);
    VMW(2); BARR(); ST(A1, W11, g1, 128); STW2(W2sA, 2, g2);    C1(A2, W12);
    VMW(5); BARR(); ST(A2, W12, g1, 160);                       C1(A0, W10); C2(W2sB, 1);
    VMW(5); BARR(); ST(A0, W10, g1, 192); STW2(W2sB, 3, g2);    C1(A1, W11);
    VMW(5); BARR(); ST(A1, W11, g1, 224);                       C1(A2, W12); C2(W2sA, 2);
    VMW(5); BARR(); ST(A2, W12, g1, 256); STW2(W2sA, 0, g2n);   C1(A0, W10);
    VMW(5); BARR(); ST(A0, W10, g1, 288);                       C1(A1, W11); C2(W2sB, 3);
    VMW(5); BARR(); ST(A1, W11, g1, 320); STW2(W2sB, 1, g2n);   C1(A2, W12);
    VMW(5); BARR(); ST(A2, W12, g1, 352);                       C1(A0, W10);
    VMW(5); BARR(); ST(A0, W10, g1n, 0);                        C1(A1, W11);
    VMW(2); BARR(); ST(A1, W11, g1n, 32);                       C1(A2, W12);
    GELU_H(bb0, bb1);
    g1 += 49152;
    g2 += 128;
  }

  // ---- post-loop: GEMM2 for chunk 11 (s0,s1 resident; stage s2,s3) ----
  VMW(0); BARR();
  C2(W2sA, 0);
  BARR();
  STW2(W2sA, 2, g2);
  C2(W2sB, 1);
  BARR();
  STW2(W2sB, 3, g2);
  VMW(3); BARR();
  C2(W2sA, 2);
  VMW(0); BARR();
  C2(W2sB, 3);
#undef ST
#undef STW2
#undef C1
#undef C2
#undef GELU_H

  __syncthreads();  // before epsw aliases the A/W1/h region

  // ---- epilogue: out = x1 + acc2 + b2 ----
  float* epsw = (float*)(pool + wv * 6400);  // [16][100] f32 per wave
  const int rr = lane >> 2, c4 = (lane & 3) * 24;
#pragma unroll
  for (int mt = 0; mt < 4; ++mt) {
#pragma unroll
    for (int nt = 0; nt < 6; ++nt)
#pragma unroll
      for (int r = 0; r < 4; ++r)
        epsw[(q * 4 + r) * 100 + nt * 16 + mr] = acc2[mt][nt][r];
    const int grow = mblk + wr1 * 64 + mt * 16 + rr;
    const int gcol = wc1 * 96 + c4;
    const float* xr = x1 + (size_t)grow * 384 + gcol;
    float* op = out + (size_t)grow * 384 + gcol;
#pragma unroll
    for (int j = 0; j < 6; ++j) {
      float4 t = *(const float4*)&epsw[rr * 100 + c4 + j * 4];
      float4 xv = *(const float4*)(xr + j * 4);
      float4 bv = *(const float4*)&b2[gcol + j * 4];
      float4 ov;
      ov.x = xv.x + t.x + bv.x;
      ov.y = xv.y + t.y + bv.y;
      ov.z = xv.z + t.z + bv.z;
      ov.w = xv.w + t.w + bv.w;
      *(float4*)(op + j * 4) = ov;
    }
  }
#undef VMW
#undef LGKM0
#undef BARR
}

// ============ attention on MFMA: 1 wave per (window, head) ==================
__global__ __launch_bounds__(64) void k_attn(const bf16* __restrict__ qkv,
                                             const float* __restrict__ tblg,
                                             bf16* __restrict__ out) {
  __shared__ __attribute__((aligned(16))) char pool[16384];
  bf16* Qs = (bf16*)pool;                                   // [64][40]
  bf16* Ks = (bf16*)(pool + 5120);                          // [64][40]
  bf16* Ps = (bf16*)pool;                                   // [64][72] alias
  float* Os = (float*)pool;                                 // [64][40] alias
  bf16* Vt = (bf16*)(pool + 10240);                         // [32][72]
  unsigned long long* msk = (unsigned long long*)(pool + 14848);  // [64]
  float* tbl = (float*)(pool + 15360);                      // [225]

  const int bid = blockIdx.x;
  const int win = bid / 12, head = bid - win * 12;
  const int lane = threadIdx.x;
  const int q = lane >> 4, mr = lane & 15;

  for (int i = lane; i < 225; i += 64) tbl[i] = tblg[i * 12 + head];

  size_t base = ((size_t)win * 12 + head) * 2048 + lane * 32;
  const uint4* qp = (const uint4*)(qkv + base);
  const uint4* kp = (const uint4*)(qkv + (size_t)12582912 + base);
  const uint4* vp = (const uint4*)(qkv + (size_t)25165824 + base);
#pragma unroll
  for (int i = 0; i < 4; ++i) *(uint4*)(Qs + lane * 40 + i * 8) = qp[i];
#pragma unroll
  for (int i = 0; i < 4; ++i) *(uint4*)(Ks + lane * 40 + i * 8) = kp[i];
  {
    union { uint4 u[4]; unsigned short h[32]; } vv;
#pragma unroll
    for (int i = 0; i < 4; ++i) vv.u[i] = vp[i];
    unsigned short* VtU = (unsigned short*)Vt;
#pragma unroll
    for (int d = 0; d < 32; ++d) VtU[d * 72 + lane] = vv.h[d];
  }
  {
    int wi = win & 15;
    int ri = lane >> 3, ci = lane & 7;
    int rh = ((wi >> 2) << 3) + ri, rw = ((wi & 3) << 3) + ci;
    int rid = (rh < 24 ? 0 : (rh < 28 ? 1 : 2)) * 3 + (rw < 24 ? 0 : (rw < 28 ? 1 : 2));
    unsigned long long m = 0;
#pragma unroll
    for (int v = 0; v < 9; ++v) {
      unsigned long long bb = __ballot(rid == v);
      if (rid == v) m = bb;
    }
    msk[lane] = m;
  }
  // single wave: LDS ops execute in program order, no barrier needed

  // ---- S = Q.K^T ----
  floatx4 sac[4][4];
#pragma unroll
  for (int i = 0; i < 4; ++i)
#pragma unroll
    for (int j = 0; j < 4; ++j) sac[i][j] = floatx4{0.f, 0.f, 0.f, 0.f};
  {
    short8 af[4], bf[4];
#pragma unroll
    for (int t = 0; t < 4; ++t) af[t] = *(const short8*)(Qs + (t * 16 + mr) * 40 + q * 8);
#pragma unroll
    for (int t = 0; t < 4; ++t) bf[t] = *(const short8*)(Ks + (t * 16 + mr) * 40 + q * 8);
    __builtin_amdgcn_s_setprio(1);
#pragma unroll
    for (int mt = 0; mt < 4; ++mt)
#pragma unroll
      for (int nt = 0; nt < 4; ++nt)
        sac[mt][nt] = __builtin_amdgcn_mfma_f32_16x16x32_bf16(af[mt], bf[nt], sac[mt][nt], 0, 0, 0);
    __builtin_amdgcn_s_setprio(0);
  }

  // ---- epilogue: scale + bias + mask + exp; row sums; P -> LDS bf16 ----
  float psum[4][4];
#pragma unroll
  for (int mt = 0; mt < 4; ++mt)
#pragma unroll
    for (int r = 0; r < 4; ++r) psum[mt][r] = 0.f;
#pragma unroll
  for (int mt = 0; mt < 4; ++mt) {
#pragma unroll
    for (int r = 0; r < 4; ++r) {
      const int i = mt * 16 + q * 4 + r;
      const unsigned long long mrow = msk[i];
      const int bi = (i >> 3) * 15 + (i & 7);
#pragma unroll
      for (int nt = 0; nt < 4; ++nt) {
        const int j = nt * 16 + mr;
        const int idx = bi + 112 - (j >> 3) * 15 - (j & 7);
        float val = sac[mt][nt][r] * 0.17677669529663687f + tbl[idx];
        float p = __expf(val);
        p = ((mrow >> j) & 1ull) ? p : 0.f;
        psum[mt][r] += p;
        Ps[i * 72 + j] = f2bf(p);
      }
    }
  }
  float inv[4][4];
#pragma unroll
  for (int mt = 0; mt < 4; ++mt)
#pragma unroll
    for (int r = 0; r < 4; ++r) {
      float s = psum[mt][r];
      s += __shfl_xor(s, 1, 64);
      s += __shfl_xor(s, 2, 64);
      s += __shfl_xor(s, 4, 64);
      s += __shfl_xor(s, 8, 64);
      inv[mt][r] = 1.f / s;
    }

  // ---- O = P.V ----
  floatx4 oac[4][2];
#pragma unroll
  for (int i = 0; i < 4; ++i)
#pragma unroll
    for (int j = 0; j < 2; ++j) oac[i][j] = floatx4{0.f, 0.f, 0.f, 0.f};
#pragma unroll
  for (int kk = 0; kk < 2; ++kk) {
    short8 ap[4], bv[2];
#pragma unroll
    for (int mt = 0; mt < 4; ++mt)
      ap[mt] = *(const short8*)(Ps + (mt * 16 + mr) * 72 + kk * 32 + q * 8);
#pragma unroll
    for (int nt = 0; nt < 2; ++nt)
      bv[nt] = *(const short8*)(Vt + (nt * 16 + mr) * 72 + kk * 32 + q * 8);
    __builtin_amdgcn_s_setprio(1);
#pragma unroll
    for (int mt = 0; mt < 4; ++mt)
#pragma unroll
      for (int nt = 0; nt < 2; ++nt)
        oac[mt][nt] = __builtin_amdgcn_mfma_f32_16x16x32_bf16(ap[mt], bv[nt], oac[mt][nt], 0, 0, 0);
    __builtin_amdgcn_s_setprio(0);
  }

  // ---- normalize + LDS round-trip -> vectorized store ----
#pragma unroll
  for (int mt = 0; mt < 4; ++mt)
#pragma unroll
    for (int nt = 0; nt < 2; ++nt)
#pragma unroll
      for (int r = 0; r < 4; ++r)
        Os[(mt * 16 + q * 4 + r) * 40 + nt * 16 + mr] = oac[mt][nt][r] * inv[mt][r];
  float ov[32];
#pragma unroll
  for (int c = 0; c < 8; ++c) {
    const int cc = c ^ (lane & 7);
    float4 t = *(const float4*)(Os + lane * 40 + cc * 4);
    ov[cc * 4 + 0] = t.x; ov[cc * 4 + 1] = t.y;
    ov[cc * 4 + 2] = t.z; ov[cc * 4 + 3] = t.w;
  }
  uint4* o4 = (uint4*)(out + ((size_t)win * 64 + lane) * CDIM + head * 32);
#pragma unroll
  for (int i = 0; i < 4; ++i) {
    uint4 pk;
    pk.x = pack2(ov[i * 8 + 0], ov[i * 8 + 1]);
    pk.y = pack2(ov[i * 8 + 2], ov[i * 8 + 3]);
    pk.z = pack2(ov[i * 8 + 4], ov[i * 8 + 5]);
    pk.w = pack2(ov[i * 8 + 6], ov[i * 8 + 7]);
    o4[i] = pk;
  }
}

extern "C" void kernel_launch(void* const* d_in, const int* in_sizes, int n_in,
                              void* d_out, int out_size, void* d_ws, size_t ws_size,
                              hipStream_t stream) {
  const float* x = (const float*)d_in[0];
  const float* n1g = (const float*)d_in[1];
  const float* n1b = (const float*)d_in[2];
  const float* qkv_w = (const float*)d_in[3];
  const float* qkv_b = (const float*)d_in[4];
  const float* reltbl = (const float*)d_in[5];
  const float* proj_w = (const float*)d_in[6];
  const float* proj_b = (const float*)d_in[7];
  const float* n2g = (const float*)d_in[8];
  const float* n2b = (const float*)d_in[9];
  const float* fc1_w = (const float*)d_in[10];
  const float* fc1_b = (const float*)d_in[11];
  const float* fc2_w = (const float*)d_in[12];
  const float* fc2_b = (const float*)d_in[13];
  float* out = (float*)d_out;

  char* p = (char*)d_ws;
  bf16* w_qkv_t = (bf16*)p;  p += (size_t)442368 * 2;
  bf16* w_proj_t = (bf16*)p; p += (size_t)147456 * 2;
  bf16* w_fc1_t = (bf16*)p;  p += (size_t)589824 * 2;
  bf16* w_fc2_t = (bf16*)p;  p += (size_t)589824 * 2;
  bf16* bufA = (bf16*)p;     p += (size_t)12582912 * 2;
  bf16* qkvb = (bf16*)p;     p += (size_t)37748736 * 2;
  bf16* attno = (bf16*)p;    p += (size_t)12582912 * 2;
  float* x1 = (float*)p;     p += (size_t)12582912 * 4;

  k_convt4<<<dim3(6912), dim3(256), 0, stream>>>(qkv_w, w_qkv_t, proj_w, w_proj_t,
                                                 fc1_w, w_fc1_t, fc2_w, w_fc2_t);

  k_ln1<<<dim3(8192), dim3(256), 0, stream>>>(x, n1g, n1b, bufA);
  k_gemm<384, 0, 9><<<dim3(9 * 256), dim3(256), 0, stream>>>(bufA, w_qkv_t, qkv_b, nullptr, qkvb);
  k_attn<<<dim3(6144), dim3(64), 0, stream>>>(qkvb, reltbl, attno);
  k_gemm<384, 1, 3><<<dim3(3 * 256), dim3(256), 0, stream>>>(attno, w_proj_t, proj_b, x, x1);
  k_ln2<<<dim3(8192), dim3(256), 0, stream>>>(x1, n2g, n2b, bufA);
  k_mlp<<<dim3(256), dim3(512), 0, stream>>>(bufA, w_fc1_t, w_fc2_t, fc1_b, fc2_b, x1, out);
}

// Round 12
// 388.358 us; speedup vs baseline: 1.1202x; 1.0313x over previous
//
#include <hip/hip_runtime.h>
#include <hip/hip_bf16.h>
#include <math.h>

typedef __hip_bfloat16 bf16;
typedef __attribute__((ext_vector_type(8))) short short8;
typedef __attribute__((ext_vector_type(4))) float floatx4;

static constexpr int TOK = 32768;
static constexpr int CDIM = 384;
static constexpr int HID = 1536;

__device__ __forceinline__ bf16 f2bf(float v) { return __float2bfloat16(v); }

__device__ __forceinline__ unsigned short bf_bits(float a) {
  bf16 h = __float2bfloat16(a);
  unsigned short u;
  __builtin_memcpy(&u, &h, 2);
  return u;
}
__device__ __forceinline__ unsigned pack2(float a, float b) {
  return (unsigned)bf_bits(a) | ((unsigned)bf_bits(b) << 16);
}

typedef const __attribute__((address_space(1))) unsigned gas_t;
typedef __attribute__((address_space(3))) unsigned las_t;
__device__ __forceinline__ void gload16(const bf16* g, const bf16* l) {
  __builtin_amdgcn_global_load_lds((gas_t*)g, (las_t*)l, 16, 0, 0);
}

// ---------------- all 4 weight conversions fused into one launch ------------
__global__ __launch_bounds__(256) void k_convt4(
    const float* __restrict__ s0, bf16* __restrict__ d0,
    const float* __restrict__ s1, bf16* __restrict__ d1,
    const float* __restrict__ s2, bf16* __restrict__ d2,
    const float* __restrict__ s3, bf16* __restrict__ d3) {
  int tid = blockIdx.x * 256 + threadIdx.x;
  const float* src; bf16* dst; int Kd, Nd, off;
  if (tid < 442368) { src = s0; dst = d0; Kd = 384; Nd = 1152; off = tid; }
  else if (tid < 589824) { src = s1; dst = d1; Kd = 384; Nd = 384; off = tid - 442368; }
  else if (tid < 1179648) { src = s2; dst = d2; Kd = 384; Nd = 1536; off = tid - 589824; }
  else { src = s3; dst = d3; Kd = 1536; Nd = 384; off = tid - 1179648; }
  int k = off / Nd, n = off - k * Nd;
  dst[(size_t)n * Kd + k] = f2bf(src[off]);
}

// ---------------- LN1 + shift + window partition (4 tokens/block) -----------
__global__ __launch_bounds__(256) void k_ln1(const float* __restrict__ x,
                                             const float* __restrict__ g,
                                             const float* __restrict__ b,
                                             bf16* __restrict__ out) {
  int wt = blockIdx.x * 4 + (threadIdx.x >> 6);
  int lane = threadIdx.x & 63;
  int win = wt >> 6, ntok = wt & 63;
  int bimg = win >> 4, wi = win & 15;
  int sh = (((wi >> 2) << 3) + (ntok >> 3) + 4) & 31;
  int sw = (((wi & 3) << 3) + (ntok & 7) + 4) & 31;
  const float* xr = x + ((size_t)bimg * 1024 + sh * 32 + sw) * CDIM;
  float v[6]; float s = 0.f, ss = 0.f;
#pragma unroll
  for (int j = 0; j < 6; ++j) {
    float t = xr[j * 64 + lane];
    v[j] = t; s += t; ss += t * t;
  }
#pragma unroll
  for (int off = 32; off > 0; off >>= 1) {
    s += __shfl_xor(s, off, 64);
    ss += __shfl_xor(ss, off, 64);
  }
  float mu = s * (1.f / 384.f);
  float var = ss * (1.f / 384.f) - mu * mu;
  float rs = rsqrtf(var + 1e-5f);
  bf16* orow = out + (size_t)wt * CDIM;
#pragma unroll
  for (int j = 0; j < 6; ++j) {
    int c = j * 64 + lane;
    orow[c] = f2bf((v[j] - mu) * rs * g[c] + b[c]);
  }
}

// ---------------- LN2 (normal token order, 4 tokens/block) ------------------
__global__ __launch_bounds__(256) void k_ln2(const float* __restrict__ x1,
                                             const float* __restrict__ g,
                                             const float* __restrict__ b,
                                             bf16* __restrict__ out) {
  int t = blockIdx.x * 4 + (threadIdx.x >> 6);
  int lane = threadIdx.x & 63;
  const float* xr = x1 + (size_t)t * CDIM;
  float v[6]; float s = 0.f, ss = 0.f;
#pragma unroll
  for (int j = 0; j < 6; ++j) {
    float q = xr[j * 64 + lane];
    v[j] = q; s += q; ss += q * q;
  }
#pragma unroll
  for (int off = 32; off > 0; off >>= 1) {
    s += __shfl_xor(s, off, 64);
    ss += __shfl_xor(ss, off, 64);
  }
  float mu = s * (1.f / 384.f);
  float var = ss * (1.f / 384.f) - mu * mu;
  float rs = rsqrtf(var + 1e-5f);
  bf16* orow = out + (size_t)t * CDIM;
#pragma unroll
  for (int j = 0; j < 6; ++j) {
    int c = j * 64 + lane;
    orow[c] = f2bf((v[j] - mu) * rs * g[c] + b[c]);
  }
}

// ============ GEMM: 128x128 tile, 3x BK=32 buffers, depth-2 counted vmcnt ===
// (round-2 proven config: 256 threads, 48 KiB LDS, vmcnt(4))
template <int K, int EPI, int NT>
__global__ __launch_bounds__(256) void k_gemm(const bf16* __restrict__ A,
                                              const bf16* __restrict__ Bt,
                                              const float* __restrict__ bias,
                                              const float* __restrict__ extra,
                                              void* __restrict__ outp) {
  __shared__ __attribute__((aligned(16))) char pool[49152];
  bf16* A0 = (bf16*)pool;
  bf16* B0 = (bf16*)(pool + 8192);
  bf16* A1 = (bf16*)(pool + 16384);
  bf16* B1 = (bf16*)(pool + 24576);
  bf16* A2 = (bf16*)(pool + 32768);
  bf16* B2 = (bf16*)(pool + 40960);

  const int tid = threadIdx.x;
  const int wv = tid >> 6, lane = tid & 63;

  const int flat = blockIdx.x;
  const int xcd = flat & 7;
  const int idx = flat >> 3;
  const int rpx = (gridDim.x >> 3) / NT;
  const int cb = idx % NT;
  const int rb = idx / NT;
  const int mblk = (xcd * rpx + rb) * 128, nblk = cb * 128;

  const int srow = lane >> 3;
  const int sc = (lane & 7) ^ srow;
  const int srow2 = 2 * srow + (sc >> 2);
  const int gco = (sc & 3) * 8;
  const bf16* gaw = A + (size_t)(mblk + wv * 32 + srow2) * K + gco;
  const bf16* gbw = Bt + (size_t)(nblk + wv * 32 + srow2) * K + gco;
  bf16* lA0 = A0 + wv * 1024; bf16* lB0 = B0 + wv * 1024;
  bf16* lA1 = A1 + wv * 1024; bf16* lB1 = B1 + wv * 1024;
  bf16* lA2 = A2 + wv * 1024; bf16* lB2 = B2 + wv * 1024;

  const int wr = wv >> 1, wc = wv & 1;
  const int mr = lane & 15, q = lane >> 4;
  const int slot8 = ((((mr & 1) << 2) | q) ^ (mr >> 1)) * 8;
  const int faOff = (wr * 32 + (mr >> 1)) * 64 + slot8;
  const int fbOff = (wc * 32 + (mr >> 1)) * 64 + slot8;

  floatx4 acc[4][4];
#pragma unroll
  for (int i = 0; i < 4; ++i)
#pragma unroll
    for (int j = 0; j < 4; ++j) acc[i][j] = floatx4{0.f, 0.f, 0.f, 0.f};

#define VM4() asm volatile("s_waitcnt vmcnt(4)" ::: "memory")
#define VM0() asm volatile("s_waitcnt vmcnt(0)" ::: "memory")
#define BAR() __builtin_amdgcn_s_barrier()

#define STAGE(LA, LB, KOFF) do { \
    gload16(gaw + (KOFF), (LA)); \
    gload16(gaw + (KOFF) + 16 * K, (LA) + 512); \
    gload16(gbw + (KOFF), (LB)); \
    gload16(gbw + (KOFF) + 16 * K, (LB) + 512); \
  } while (0)

#define COMPUTE(ABASE, BBASE) do { \
    short8 a_[4], b_[4]; \
    _Pragma("unroll") \
    for (int mt = 0; mt < 4; ++mt) a_[mt] = *(const short8*)((ABASE) + faOff + mt * 512); \
    _Pragma("unroll") \
    for (int nt = 0; nt < 4; ++nt) b_[nt] = *(const short8*)((BBASE) + fbOff + nt * 512); \
    _Pragma("unroll") \
    for (int mt = 0; mt < 4; ++mt) \
      _Pragma("unroll") \
      for (int nt = 0; nt < 4; ++nt) \
        acc[mt][nt] = __builtin_amdgcn_mfma_f32_16x16x32_bf16(a_[mt], b_[nt], acc[mt][nt], 0, 0, 0); \
  } while (0)

  STAGE(lA0, lB0, 0);
  STAGE(lA1, lB1, 32);
  for (int k0 = 0; k0 < K - 96; k0 += 96) {
    VM4(); BAR(); STAGE(lA2, lB2, k0 + 64);  COMPUTE(A0, B0);
    VM4(); BAR(); STAGE(lA0, lB0, k0 + 96);  COMPUTE(A1, B1);
    VM4(); BAR(); STAGE(lA1, lB1, k0 + 128); COMPUTE(A2, B2);
  }
  VM4(); BAR(); STAGE(lA2, lB2, K - 32); COMPUTE(A0, B0);
  VM4(); BAR();                          COMPUTE(A1, B1);
  VM0(); BAR();                          COMPUTE(A2, B2);
#undef STAGE
#undef COMPUTE
#undef VM4
#undef VM0
#undef BAR

  __syncthreads();
  float* epsw = (float*)pool + wv * (16 * 68);
  const int rr = lane >> 2, c0 = (lane & 3) * 16;
#pragma unroll
  for (int mt = 0; mt < 4; ++mt) {
#pragma unroll
    for (int nt = 0; nt < 4; ++nt)
#pragma unroll
      for (int r = 0; r < 4; ++r)
        epsw[(q * 4 + r) * 68 + nt * 16 + mr] = acc[mt][nt][r];
    float v[16];
#pragma unroll
    for (int j = 0; j < 4; ++j) {
      float4 t = *(const float4*)&epsw[rr * 68 + c0 + j * 4];
      v[j * 4 + 0] = t.x; v[j * 4 + 1] = t.y; v[j * 4 + 2] = t.z; v[j * 4 + 3] = t.w;
    }
    const int grow = mblk + wr * 64 + mt * 16 + rr;
    const int gcol = nblk + wc * 64 + c0;

    if constexpr (EPI == 0) {
      int win = grow >> 6, ntok = grow & 63;
      int s = gcol / 384;
      int rem = gcol - s * 384;
      int h = rem >> 5, d0 = rem & 31;
      bf16* op = (bf16*)outp + (((size_t)s * 512 + win) * 12 + h) * 2048 + ntok * 32 + d0;
      uint4 pk;
      float bv[16];
#pragma unroll
      for (int j = 0; j < 16; ++j) bv[j] = v[j] + bias[gcol + j];
      pk.x = pack2(bv[0], bv[1]); pk.y = pack2(bv[2], bv[3]);
      pk.z = pack2(bv[4], bv[5]); pk.w = pack2(bv[6], bv[7]);
      *(uint4*)op = pk;
      pk.x = pack2(bv[8], bv[9]); pk.y = pack2(bv[10], bv[11]);
      pk.z = pack2(bv[12], bv[13]); pk.w = pack2(bv[14], bv[15]);
      *(uint4*)(op + 8) = pk;
    } else if constexpr (EPI == 1) {
      int win = grow >> 6, ntok = grow & 63;
      int bimg = win >> 4, wi = win & 15;
      int hh = (((wi >> 2) << 3) + (ntok >> 3) + 4) & 31;
      int ww = (((wi & 3) << 3) + (ntok & 7) + 4) & 31;
      size_t t = (size_t)bimg * 1024 + hh * 32 + ww;
      float* op = (float*)outp + t * CDIM + gcol;
      const float* xr = extra + t * CDIM + gcol;
#pragma unroll
      for (int j = 0; j < 4; ++j) {
        float4 xv = *(const float4*)(xr + j * 4);
        float4 ov;
        ov.x = xv.x + v[j * 4 + 0] + bias[gcol + j * 4 + 0];
        ov.y = xv.y + v[j * 4 + 1] + bias[gcol + j * 4 + 1];
        ov.z = xv.z + v[j * 4 + 2] + bias[gcol + j * 4 + 2];
        ov.w = xv.w + v[j * 4 + 3] + bias[gcol + j * 4 + 3];
        *(float4*)(op + j * 4) = ov;
      }
    }
  }
}

// ===================== fused MLP: x1 + fc2(gelu(fc1(ln2))) ==================
// round-5 proven config (124 us, VGPR 120, no spill): 1 block / 128 tokens,
// 8 waves, grid 256 = 1 block/CU.  12 hidden chunks of 128: GEMM1 (K=384,
// 3-buf rotation, counted vmcnt) -> GELU in-reg -> h in LDS (XOR layout) ->
// GEMM2 (4 K-slices, W2sA/W2sB ping-pong, counted vmcnt) into persistent
// acc2[4][6].  hidden never touches HBM.
// NOTE (rounds 7-11): interleaving GEMM2 into GEMM1 is register-infeasible
// (128 acc + ~160 transient > 256 unified cap at 2 waves/SIMD -> spill);
// BK=64 + direct-L2 W2 loses the depth-2 pipeline (166 us).  This schedule
// is the measured optimum of the family.
__global__ __launch_bounds__(512, 2) void k_mlp(const bf16* __restrict__ A,
                                                const bf16* __restrict__ W1t,
                                                const bf16* __restrict__ W2t,
                                                const float* __restrict__ b1,
                                                const float* __restrict__ b2,
                                                const float* __restrict__ x1,
                                                float* __restrict__ out) {
  __shared__ __attribute__((aligned(16))) char pool[131072];
  bf16* A0 = (bf16*)pool;
  bf16* A1 = (bf16*)(pool + 8192);
  bf16* A2 = (bf16*)(pool + 16384);
  bf16* W10 = (bf16*)(pool + 24576);
  bf16* W11 = (bf16*)(pool + 32768);
  bf16* W12 = (bf16*)(pool + 40960);
  bf16* hs = (bf16*)(pool + 49152);     // [128 tok][16 slots][8], XOR layout
  bf16* W2sA = (bf16*)(pool + 81920);   // [192 rowpair][64] = 24 KiB
  bf16* W2sB = (bf16*)(pool + 106496);  // [192 rowpair][64] = 24 KiB

  const int tid = threadIdx.x;
  const int wv = tid >> 6, lane = tid & 63;
  const int mblk = blockIdx.x * 128;

  const int srow = lane >> 3;
  const int sc = (lane & 7) ^ srow;
  const int srow2 = 2 * srow + (sc >> 2);
  const int gco = (sc & 3) * 8;

  const bf16* ga = A + (size_t)(mblk + wv * 16 + srow2) * 384 + gco;
  const bf16* g1 = W1t + (size_t)(wv * 16 + srow2) * 384 + gco;
  const bf16* g2 = W2t + (size_t)(wv * 48 + srow2) * 1536 + gco;

  const int wr1 = wv >> 2, wc1 = wv & 3;
  const int mr = lane & 15, q = lane >> 4;
  const int slot8 = ((((mr & 1) << 2) | q) ^ (mr >> 1)) * 8;
  const int faOff1 = (wr1 * 32 + (mr >> 1)) * 64 + slot8;
  const int fbOff1 = (wc1 * 16 + (mr >> 1)) * 64 + slot8;
  const int fbOff2 = (wc1 * 48 + (mr >> 1)) * 64 + slot8;
  const size_t hb = (size_t)(wr1 * 64 + mr) * 128;
  int px[4];
#pragma unroll
  for (int kk = 0; kk < 4; ++kk)
    px[kk] = (((kk & 2) << 2) | ((((kk & 1) << 2) | q) ^ (mr & 7))) * 8;

  floatx4 acc1[4][2];
  floatx4 acc2[4][6];
#pragma unroll
  for (int i = 0; i < 4; ++i) {
#pragma unroll
    for (int j = 0; j < 2; ++j) acc1[i][j] = floatx4{0.f, 0.f, 0.f, 0.f};
#pragma unroll
    for (int j = 0; j < 6; ++j) acc2[i][j] = floatx4{0.f, 0.f, 0.f, 0.f};
  }

#define VMW(N) asm volatile("s_waitcnt vmcnt(" #N ")" ::: "memory")
#define LGKM0() asm volatile("s_waitcnt lgkmcnt(0)" ::: "memory")
#define BARR() __builtin_amdgcn_s_barrier()
#define ST(ABUF, WBUF, G1P, KO) do { \
    gload16(ga + (KO), (ABUF) + wv * 512); \
    gload16((G1P) + (KO), (WBUF) + wv * 512); \
  } while (0)
#define STW2(BUF, KK) do { \
    _Pragma("unroll") \
    for (int g = 0; g < 3; ++g) \
      gload16(g2 + (KK) * 32 + (size_t)g * 16 * 1536, (BUF) + wv * 1536 + g * 512); \
  } while (0)
#define C1(AB, WB) do { \
    short8 a_[4], b_[2]; \
    _Pragma("unroll") \
    for (int mt = 0; mt < 4; ++mt) a_[mt] = *(const short8*)((AB) + faOff1 + mt * 512); \
    b_[0] = *(const short8*)((WB) + fbOff1); \
    b_[1] = *(const short8*)((WB) + fbOff1 + 512); \
    _Pragma("unroll") \
    for (int mt = 0; mt < 4; ++mt) \
      _Pragma("unroll") \
      for (int nt = 0; nt < 2; ++nt) \
        acc1[mt][nt] = __builtin_amdgcn_mfma_f32_16x16x32_bf16(a_[mt], b_[nt], acc1[mt][nt], 0, 0, 0); \
  } while (0)
#define C2(BUF, KK) do { \
    short8 ha[4], wb[6]; \
    _Pragma("unroll") \
    for (int mt = 0; mt < 4; ++mt) \
      ha[mt] = *(const short8*)(hs + hb + mt * 2048 + px[KK]); \
    _Pragma("unroll") \
    for (int nt = 0; nt < 6; ++nt) \
      wb[nt] = *(const short8*)((BUF) + fbOff2 + nt * 512); \
    _Pragma("unroll") \
    for (int mt = 0; mt < 4; ++mt) \
      _Pragma("unroll") \
      for (int nt = 0; nt < 6; ++nt) \
        acc2[mt][nt] = __builtin_amdgcn_mfma_f32_16x16x32_bf16(ha[mt], wb[nt], acc2[mt][nt], 0, 0, 0); \
  } while (0)
// GELU + bias -> h (XOR layout), rezero acc1
#define GELU_H(BB0, BB1) do { \
    _Pragma("unroll") \
    for (int mt = 0; mt < 4; ++mt) { \
      const int tokb = wr1 * 64 + mt * 16 + q * 4; \
      _Pragma("unroll") \
      for (int nt = 0; nt < 2; ++nt) { \
        const float bb = nt ? (BB1) : (BB0); \
        const int sw = wc1 * 4 + nt * 2 + (mr >> 3); \
        const int s8 = sw & 8, s7 = sw & 7; \
        _Pragma("unroll") \
        for (int r = 0; r < 4; ++r) { \
          float z = acc1[mt][nt][r] + bb; \
          float t2 = z * z; \
          float cp = __builtin_fmaf(t2, -0.0713548162f, -1.5957691216f); \
          float e = __expf(z * cp); \
          float gl = z * __builtin_amdgcn_rcpf(1.f + e); \
          const int t7 = ((q & 1) << 2) | r; \
          hs[(size_t)(tokb + r) * 128 + (s8 | (s7 ^ t7)) * 8 + (mr & 7)] = f2bf(gl); \
        } \
        acc1[mt][nt] = floatx4{0.f, 0.f, 0.f, 0.f}; \
      } \
    } \
    LGKM0(); \
  } while (0)

  // prologue: stages for steps 0,1 of chunk 0
  ST(A0, W10, g1, 0);
  ST(A1, W11, g1, 32);

  for (int ci = 0; ci < 12; ++ci) {
    BARR();  // prev GEMM2 reads of hs/W2sA/W2sB all complete
    // bias values for this chunk (loads issue early; consumed in GELU)
    const int cb = ci * 128;
    float bb0 = b1[cb + wc1 * 32 + mr];
    float bb1 = b1[cb + wc1 * 32 + 16 + mr];
    STW2(W2sA, 0);  // slice0: 3 gloads, drained by step2's vmcnt(2)

    const bf16* g1n = g1 + 49152;
    VMW(5); BARR(); ST(A2, W12, g1, 64);   C1(A0, W10);
    VMW(5); BARR(); ST(A0, W10, g1, 96);   C1(A1, W11);
    VMW(2); BARR(); ST(A1, W11, g1, 128);  C1(A2, W12);
    VMW(2); BARR(); ST(A2, W12, g1, 160);  C1(A0, W10);
    VMW(2); BARR(); ST(A0, W10, g1, 192);  C1(A1, W11);
    VMW(2); BARR(); ST(A1, W11, g1, 224);  C1(A2, W12);
    VMW(2); BARR(); ST(A2, W12, g1, 256);  C1(A0, W10);
    VMW(2); BARR(); ST(A0, W10, g1, 288);  C1(A1, W11);
    VMW(2); BARR(); ST(A1, W11, g1, 320);  C1(A2, W12);
    VMW(2); BARR(); ST(A2, W12, g1, 352);  C1(A0, W10);
    VMW(2); BARR(); ST(A0, W10, g1n, 0);   C1(A1, W11);
    VMW(2); BARR(); ST(A1, W11, g1n, 32);  C1(A2, W12);

    GELU_H(bb0, bb1);
    __syncthreads();

    // ---- GEMM2: 4 slices, W2sA/W2sB ping-pong, counted vmcnt ----
    STW2(W2sB, 1);
    C2(W2sA, 0);            // slice0 drained at step2 + barriers since
    BARR();                 // all waves done reading W2sA
    STW2(W2sA, 2);
    VMW(3); BARR();         // slice1 complete (leaves slice2 in flight)
    C2(W2sB, 1);
    BARR();                 // all waves done reading W2sB
    STW2(W2sB, 3);
    VMW(3); BARR();         // slice2 complete (leaves slice3 in flight)
    C2(W2sA, 2);
    VMW(0); BARR();         // slice3 complete
    C2(W2sB, 3);

    g1 += 49152;
    g2 += 128;
  }
#undef ST
#undef STW2
#undef C1
#undef C2
#undef GELU_H

  VMW(0);           // drain stray last-chunk prefetches
  __syncthreads();  // before epsw aliases the A/W1/h region

  // ---- epilogue: out = x1 + acc2 + b2 ----
  float* epsw = (float*)(pool + wv * 6400);  // [16][100] f32 per wave
  const int rr = lane >> 2, c4 = (lane & 3) * 24;
#pragma unroll
  for (int mt = 0; mt < 4; ++mt) {
#pragma unroll
    for (int nt = 0; nt < 6; ++nt)
#pragma unroll
      for (int r = 0; r < 4; ++r)
        epsw[(q * 4 + r) * 100 + nt * 16 + mr] = acc2[mt][nt][r];
    const int grow = mblk + wr1 * 64 + mt * 16 + rr;
    const int gcol = wc1 * 96 + c4;
    const float* xr = x1 + (size_t)grow * 384 + gcol;
    float* op = out + (size_t)grow * 384 + gcol;
#pragma unroll
    for (int j = 0; j < 6; ++j) {
      float4 t = *(const float4*)&epsw[rr * 100 + c4 + j * 4];
      float4 xv = *(const float4*)(xr + j * 4);
      float4 bv = *(const float4*)&b2[gcol + j * 4];
      float4 ov;
      ov.x = xv.x + t.x + bv.x;
      ov.y = xv.y + t.y + bv.y;
      ov.z = xv.z + t.z + bv.z;
      ov.w = xv.w + t.w + bv.w;
      *(float4*)(op + j * 4) = ov;
    }
  }
#undef VMW
#undef LGKM0
#undef BARR
}

// ============ attention on MFMA: 1 wave per (window, head) ==================
__global__ __launch_bounds__(64) void k_attn(const bf16* __restrict__ qkv,
                                             const float* __restrict__ tblg,
                                             bf16* __restrict__ out) {
  __shared__ __attribute__((aligned(16))) char pool[16384];
  bf16* Qs = (bf16*)pool;                                   // [64][40]
  bf16* Ks = (bf16*)(pool + 5120);                          // [64][40]
  bf16* Ps = (bf16*)pool;                                   // [64][72] alias
  float* Os = (float*)pool;                                 // [64][40] alias
  bf16* Vt = (bf16*)(pool + 10240);                         // [32][72]
  unsigned long long* msk = (unsigned long long*)(pool + 14848);  // [64]
  float* tbl = (float*)(pool + 15360);                      // [225]

  const int bid = blockIdx.x;
  const int win = bid / 12, head = bid - win * 12;
  const int lane = threadIdx.x;
  const int q = lane >> 4, mr = lane & 15;

  for (int i = lane; i < 225; i += 64) tbl[i] = tblg[i * 12 + head];

  size_t base = ((size_t)win * 12 + head) * 2048 + lane * 32;
  const uint4* qp = (const uint4*)(qkv + base);
  const uint4* kp = (const uint4*)(qkv + (size_t)12582912 + base);
  const uint4* vp = (const uint4*)(qkv + (size_t)25165824 + base);
#pragma unroll
  for (int i = 0; i < 4; ++i) *(uint4*)(Qs + lane * 40 + i * 8) = qp[i];
#pragma unroll
  for (int i = 0; i < 4; ++i) *(uint4*)(Ks + lane * 40 + i * 8) = kp[i];
  {
    union { uint4 u[4]; unsigned short h[32]; } vv;
#pragma unroll
    for (int i = 0; i < 4; ++i) vv.u[i] = vp[i];
    unsigned short* VtU = (unsigned short*)Vt;
#pragma unroll
    for (int d = 0; d < 32; ++d) VtU[d * 72 + lane] = vv.h[d];
  }
  {
    int wi = win & 15;
    int ri = lane >> 3, ci = lane & 7;
    int rh = ((wi >> 2) << 3) + ri, rw = ((wi & 3) << 3) + ci;
    int rid = (rh < 24 ? 0 : (rh < 28 ? 1 : 2)) * 3 + (rw < 24 ? 0 : (rw < 28 ? 1 : 2));
    unsigned long long m = 0;
#pragma unroll
    for (int v = 0; v < 9; ++v) {
      unsigned long long bb = __ballot(rid == v);
      if (rid == v) m = bb;
    }
    msk[lane] = m;
  }
  // single wave: LDS ops execute in program order, no barrier needed

  // ---- S = Q.K^T ----
  floatx4 sac[4][4];
#pragma unroll
  for (int i = 0; i < 4; ++i)
#pragma unroll
    for (int j = 0; j < 4; ++j) sac[i][j] = floatx4{0.f, 0.f, 0.f, 0.f};
  {
    short8 af[4], bf[4];
#pragma unroll
    for (int t = 0; t < 4; ++t) af[t] = *(const short8*)(Qs + (t * 16 + mr) * 40 + q * 8);
#pragma unroll
    for (int t = 0; t < 4; ++t) bf[t] = *(const short8*)(Ks + (t * 16 + mr) * 40 + q * 8);
#pragma unroll
    for (int mt = 0; mt < 4; ++mt)
#pragma unroll
      for (int nt = 0; nt < 4; ++nt)
        sac[mt][nt] = __builtin_amdgcn_mfma_f32_16x16x32_bf16(af[mt], bf[nt], sac[mt][nt], 0, 0, 0);
  }

  // ---- epilogue: scale + bias + mask + exp; row sums; P -> LDS bf16 ----
  float psum[4][4];
#pragma unroll
  for (int mt = 0; mt < 4; ++mt)
#pragma unroll
    for (int r = 0; r < 4; ++r) psum[mt][r] = 0.f;
#pragma unroll
  for (int mt = 0; mt < 4; ++mt) {
#pragma unroll
    for (int r = 0; r < 4; ++r) {
      const int i = mt * 16 + q * 4 + r;
      const unsigned long long mrow = msk[i];
      const int bi = (i >> 3) * 15 + (i & 7);
#pragma unroll
      for (int nt = 0; nt < 4; ++nt) {
        const int j = nt * 16 + mr;
        const int idx = bi + 112 - (j >> 3) * 15 - (j & 7);
        float val = sac[mt][nt][r] * 0.17677669529663687f + tbl[idx];
        float p = __expf(val);
        p = ((mrow >> j) & 1ull) ? p : 0.f;
        psum[mt][r] += p;
        Ps[i * 72 + j] = f2bf(p);
      }
    }
  }
  float inv[4][4];
#pragma unroll
  for (int mt = 0; mt < 4; ++mt)
#pragma unroll
    for (int r = 0; r < 4; ++r) {
      float s = psum[mt][r];
      s += __shfl_xor(s, 1, 64);
      s += __shfl_xor(s, 2, 64);
      s += __shfl_xor(s, 4, 64);
      s += __shfl_xor(s, 8, 64);
      inv[mt][r] = 1.f / s;
    }

  // ---- O = P.V ----
  floatx4 oac[4][2];
#pragma unroll
  for (int i = 0; i < 4; ++i)
#pragma unroll
    for (int j = 0; j < 2; ++j) oac[i][j] = floatx4{0.f, 0.f, 0.f, 0.f};
#pragma unroll
  for (int kk = 0; kk < 2; ++kk) {
    short8 ap[4], bv[2];
#pragma unroll
    for (int mt = 0; mt < 4; ++mt)
      ap[mt] = *(const short8*)(Ps + (mt * 16 + mr) * 72 + kk * 32 + q * 8);
#pragma unroll
    for (int nt = 0; nt < 2; ++nt)
      bv[nt] = *(const short8*)(Vt + (nt * 16 + mr) * 72 + kk * 32 + q * 8);
#pragma unroll
    for (int mt = 0; mt < 4; ++mt)
#pragma unroll
      for (int nt = 0; nt < 2; ++nt)
        oac[mt][nt] = __builtin_amdgcn_mfma_f32_16x16x32_bf16(ap[mt], bv[nt], oac[mt][nt], 0, 0, 0);
  }

  // ---- normalize + LDS round-trip -> vectorized store ----
#pragma unroll
  for (int mt = 0; mt < 4; ++mt)
#pragma unroll
    for (int nt = 0; nt < 2; ++nt)
#pragma unroll
      for (int r = 0; r < 4; ++r)
        Os[(mt * 16 + q * 4 + r) * 40 + nt * 16 + mr] = oac[mt][nt][r] * inv[mt][r];
  float ov[32];
#pragma unroll
  for (int c = 0; c < 8; ++c) {
    const int cc = c ^ (lane & 7);
    float4 t = *(const float4*)(Os + lane * 40 + cc * 4);
    ov[cc * 4 + 0] = t.x; ov[cc * 4 + 1] = t.y;
    ov[cc * 4 + 2] = t.z; ov[cc * 4 + 3] = t.w;
  }
  uint4* o4 = (uint4*)(out + ((size_t)win * 64 + lane) * CDIM + head * 32);
#pragma unroll
  for (int i = 0; i < 4; ++i) {
    uint4 pk;
    pk.x = pack2(ov[i * 8 + 0], ov[i * 8 + 1]);
    pk.y = pack2(ov[i * 8 + 2], ov[i * 8 + 3]);
    pk.z = pack2(ov[i * 8 + 4], ov[i * 8 + 5]);
    pk.w = pack2(ov[i * 8 + 6], ov[i * 8 + 7]);
    o4[i] = pk;
  }
}

extern "C" void kernel_launch(void* const* d_in, const int* in_sizes, int n_in,
                              void* d_out, int out_size, void* d_ws, size_t ws_size,
                              hipStream_t stream) {
  const float* x = (const float*)d_in[0];
  const float* n1g = (const float*)d_in[1];
  const float* n1b = (const float*)d_in[2];
  const float* qkv_w = (const float*)d_in[3];
  const float* qkv_b = (const float*)d_in[4];
  const float* reltbl = (const float*)d_in[5];
  const float* proj_w = (const float*)d_in[6];
  const float* proj_b = (const float*)d_in[7];
  const float* n2g = (const float*)d_in[8];
  const float* n2b = (const float*)d_in[9];
  const float* fc1_w = (const float*)d_in[10];
  const float* fc1_b = (const float*)d_in[11];
  const float* fc2_w = (const float*)d_in[12];
  const float* fc2_b = (const float*)d_in[13];
  float* out = (float*)d_out;

  char* p = (char*)d_ws;
  bf16* w_qkv_t = (bf16*)p;  p += (size_t)442368 * 2;
  bf16* w_proj_t = (bf16*)p; p += (size_t)147456 * 2;
  bf16* w_fc1_t = (bf16*)p;  p += (size_t)589824 * 2;
  bf16* w_fc2_t = (bf16*)p;  p += (size_t)589824 * 2;
  bf16* bufA = (bf16*)p;     p += (size_t)12582912 * 2;
  bf16* qkvb = (bf16*)p;     p += (size_t)37748736 * 2;
  bf16* attno = (bf16*)p;    p += (size_t)12582912 * 2;
  float* x1 = (float*)p;     p += (size_t)12582912 * 4;

  k_convt4<<<dim3(6912), dim3(256), 0, stream>>>(qkv_w, w_qkv_t, proj_w, w_proj_t,
                                                 fc1_w, w_fc1_t, fc2_w, w_fc2_t);

  k_ln1<<<dim3(8192), dim3(256), 0, stream>>>(x, n1g, n1b, bufA);
  k_gemm<384, 0, 9><<<dim3(9 * 256), dim3(256), 0, stream>>>(bufA, w_qkv_t, qkv_b, nullptr, qkvb);
  k_attn<<<dim3(6144), dim3(64), 0, stream>>>(qkvb, reltbl, attno);
  k_gemm<384, 1, 3><<<dim3(3 * 256), dim3(256), 0, stream>>>(attno, w_proj_t, proj_b, x, x1);
  k_ln2<<<dim3(8192), dim3(256), 0, stream>>>(x1, n2g, n2b, bufA);
  k_mlp<<<dim3(256), dim3(512), 0, stream>>>(bufA, w_fc1_t, w_fc2_t, fc1_b, fc2_b, x1, out);
}

// Round 13
// 372.410 us; speedup vs baseline: 1.1681x; 1.0428x over previous
//
#include <hip/hip_runtime.h>
#include <hip/hip_bf16.h>
#include <math.h>

typedef __hip_bfloat16 bf16;
typedef __attribute__((ext_vector_type(8))) short short8;
typedef __attribute__((ext_vector_type(4))) float floatx4;

static constexpr int TOK = 32768;
static constexpr int CDIM = 384;
static constexpr int HID = 1536;

__device__ __forceinline__ bf16 f2bf(float v) { return __float2bfloat16(v); }

__device__ __forceinline__ unsigned short bf_bits(float a) {
  bf16 h = __float2bfloat16(a);
  unsigned short u;
  __builtin_memcpy(&u, &h, 2);
  return u;
}
__device__ __forceinline__ unsigned pack2(float a, float b) {
  return (unsigned)bf_bits(a) | ((unsigned)bf_bits(b) << 16);
}
__device__ __forceinline__ float bfl(unsigned u) {
  unsigned w = u << 16; float f; __builtin_memcpy(&f, &w, 4); return f;
}
__device__ __forceinline__ float bfh(unsigned u) {
  unsigned w = u & 0xffff0000u; float f; __builtin_memcpy(&f, &w, 4); return f;
}

typedef const __attribute__((address_space(1))) unsigned gas_t;
typedef __attribute__((address_space(3))) unsigned las_t;
__device__ __forceinline__ void gload16(const bf16* g, const bf16* l) {
  __builtin_amdgcn_global_load_lds((gas_t*)g, (las_t*)l, 16, 0, 0);
}

// ------- fused pre-pass: weight conversions (blocks 0..6911) + LN1/shift
// (blocks 6912..15103).  Independent work, one launch. -----------------------
__global__ __launch_bounds__(256) void k_pre(
    const float* __restrict__ s0, bf16* __restrict__ d0,
    const float* __restrict__ s1, bf16* __restrict__ d1,
    const float* __restrict__ s2, bf16* __restrict__ d2,
    const float* __restrict__ s3, bf16* __restrict__ d3,
    const float* __restrict__ x, const float* __restrict__ g,
    const float* __restrict__ b, bf16* __restrict__ out) {
  if (blockIdx.x < 6912) {
    int tid = blockIdx.x * 256 + threadIdx.x;
    const float* src; bf16* dst; int Kd, Nd, off;
    if (tid < 442368) { src = s0; dst = d0; Kd = 384; Nd = 1152; off = tid; }
    else if (tid < 589824) { src = s1; dst = d1; Kd = 384; Nd = 384; off = tid - 442368; }
    else if (tid < 1179648) { src = s2; dst = d2; Kd = 384; Nd = 1536; off = tid - 589824; }
    else { src = s3; dst = d3; Kd = 1536; Nd = 384; off = tid - 1179648; }
    int k = off / Nd, n = off - k * Nd;
    dst[(size_t)n * Kd + k] = f2bf(src[off]);
    return;
  }
  int wt = (blockIdx.x - 6912) * 4 + (threadIdx.x >> 6);
  int lane = threadIdx.x & 63;
  int win = wt >> 6, ntok = wt & 63;
  int bimg = win >> 4, wi = win & 15;
  int sh = (((wi >> 2) << 3) + (ntok >> 3) + 4) & 31;
  int sw = (((wi & 3) << 3) + (ntok & 7) + 4) & 31;
  const float* xr = x + ((size_t)bimg * 1024 + sh * 32 + sw) * CDIM;
  float v[6]; float s = 0.f, ss = 0.f;
#pragma unroll
  for (int j = 0; j < 6; ++j) {
    float t = xr[j * 64 + lane];
    v[j] = t; s += t; ss += t * t;
  }
#pragma unroll
  for (int off = 32; off > 0; off >>= 1) {
    s += __shfl_xor(s, off, 64);
    ss += __shfl_xor(ss, off, 64);
  }
  float mu = s * (1.f / 384.f);
  float var = ss * (1.f / 384.f) - mu * mu;
  float rs = rsqrtf(var + 1e-5f);
  bf16* orow = out + (size_t)wt * CDIM;
#pragma unroll
  for (int j = 0; j < 6; ++j) {
    int c = j * 64 + lane;
    orow[c] = f2bf((v[j] - mu) * rs * g[c] + b[c]);
  }
}

// ---------------- LN2 (reads bf16 x1, normal token order, 4 tokens/block) ---
__global__ __launch_bounds__(256) void k_ln2(const bf16* __restrict__ x1,
                                             const float* __restrict__ g,
                                             const float* __restrict__ b,
                                             bf16* __restrict__ out) {
  int t = blockIdx.x * 4 + (threadIdx.x >> 6);
  int lane = threadIdx.x & 63;
  const bf16* xr = x1 + (size_t)t * CDIM;
  float v[6]; float s = 0.f, ss = 0.f;
#pragma unroll
  for (int j = 0; j < 6; ++j) {
    float q = __bfloat162float(xr[j * 64 + lane]);
    v[j] = q; s += q; ss += q * q;
  }
#pragma unroll
  for (int off = 32; off > 0; off >>= 1) {
    s += __shfl_xor(s, off, 64);
    ss += __shfl_xor(ss, off, 64);
  }
  float mu = s * (1.f / 384.f);
  float var = ss * (1.f / 384.f) - mu * mu;
  float rs = rsqrtf(var + 1e-5f);
  bf16* orow = out + (size_t)t * CDIM;
#pragma unroll
  for (int j = 0; j < 6; ++j) {
    int c = j * 64 + lane;
    orow[c] = f2bf((v[j] - mu) * rs * g[c] + b[c]);
  }
}

// ============ GEMM: 128x128 tile, 3x BK=32 buffers, depth-2 counted vmcnt ===
// (round-2 proven config: 256 threads, 48 KiB LDS, vmcnt(4))
// EPI==0: qkv scatter (bf16).  EPI==1: x1 = x + out + bias, written BF16.
template <int K, int EPI, int NT>
__global__ __launch_bounds__(256) void k_gemm(const bf16* __restrict__ A,
                                              const bf16* __restrict__ Bt,
                                              const float* __restrict__ bias,
                                              const float* __restrict__ extra,
                                              void* __restrict__ outp) {
  __shared__ __attribute__((aligned(16))) char pool[49152];
  bf16* A0 = (bf16*)pool;
  bf16* B0 = (bf16*)(pool + 8192);
  bf16* A1 = (bf16*)(pool + 16384);
  bf16* B1 = (bf16*)(pool + 24576);
  bf16* A2 = (bf16*)(pool + 32768);
  bf16* B2 = (bf16*)(pool + 40960);

  const int tid = threadIdx.x;
  const int wv = tid >> 6, lane = tid & 63;

  const int flat = blockIdx.x;
  const int xcd = flat & 7;
  const int idx = flat >> 3;
  const int rpx = (gridDim.x >> 3) / NT;
  const int cb = idx % NT;
  const int rb = idx / NT;
  const int mblk = (xcd * rpx + rb) * 128, nblk = cb * 128;

  const int srow = lane >> 3;
  const int sc = (lane & 7) ^ srow;
  const int srow2 = 2 * srow + (sc >> 2);
  const int gco = (sc & 3) * 8;
  const bf16* gaw = A + (size_t)(mblk + wv * 32 + srow2) * K + gco;
  const bf16* gbw = Bt + (size_t)(nblk + wv * 32 + srow2) * K + gco;
  bf16* lA0 = A0 + wv * 1024; bf16* lB0 = B0 + wv * 1024;
  bf16* lA1 = A1 + wv * 1024; bf16* lB1 = B1 + wv * 1024;
  bf16* lA2 = A2 + wv * 1024; bf16* lB2 = B2 + wv * 1024;

  const int wr = wv >> 1, wc = wv & 1;
  const int mr = lane & 15, q = lane >> 4;
  const int slot8 = ((((mr & 1) << 2) | q) ^ (mr >> 1)) * 8;
  const int faOff = (wr * 32 + (mr >> 1)) * 64 + slot8;
  const int fbOff = (wc * 32 + (mr >> 1)) * 64 + slot8;

  floatx4 acc[4][4];
#pragma unroll
  for (int i = 0; i < 4; ++i)
#pragma unroll
    for (int j = 0; j < 4; ++j) acc[i][j] = floatx4{0.f, 0.f, 0.f, 0.f};

#define VM4() asm volatile("s_waitcnt vmcnt(4)" ::: "memory")
#define VM0() asm volatile("s_waitcnt vmcnt(0)" ::: "memory")
#define BAR() __builtin_amdgcn_s_barrier()

#define STAGE(LA, LB, KOFF) do { \
    gload16(gaw + (KOFF), (LA)); \
    gload16(gaw + (KOFF) + 16 * K, (LA) + 512); \
    gload16(gbw + (KOFF), (LB)); \
    gload16(gbw + (KOFF) + 16 * K, (LB) + 512); \
  } while (0)

#define COMPUTE(ABASE, BBASE) do { \
    short8 a_[4], b_[4]; \
    _Pragma("unroll") \
    for (int mt = 0; mt < 4; ++mt) a_[mt] = *(const short8*)((ABASE) + faOff + mt * 512); \
    _Pragma("unroll") \
    for (int nt = 0; nt < 4; ++nt) b_[nt] = *(const short8*)((BBASE) + fbOff + nt * 512); \
    _Pragma("unroll") \
    for (int mt = 0; mt < 4; ++mt) \
      _Pragma("unroll") \
      for (int nt = 0; nt < 4; ++nt) \
        acc[mt][nt] = __builtin_amdgcn_mfma_f32_16x16x32_bf16(a_[mt], b_[nt], acc[mt][nt], 0, 0, 0); \
  } while (0)

  STAGE(lA0, lB0, 0);
  STAGE(lA1, lB1, 32);
  for (int k0 = 0; k0 < K - 96; k0 += 96) {
    VM4(); BAR(); STAGE(lA2, lB2, k0 + 64);  COMPUTE(A0, B0);
    VM4(); BAR(); STAGE(lA0, lB0, k0 + 96);  COMPUTE(A1, B1);
    VM4(); BAR(); STAGE(lA1, lB1, k0 + 128); COMPUTE(A2, B2);
  }
  VM4(); BAR(); STAGE(lA2, lB2, K - 32); COMPUTE(A0, B0);
  VM4(); BAR();                          COMPUTE(A1, B1);
  VM0(); BAR();                          COMPUTE(A2, B2);
#undef STAGE
#undef COMPUTE
#undef VM4
#undef VM0
#undef BAR

  __syncthreads();
  float* epsw = (float*)pool + wv * (16 * 68);
  const int rr = lane >> 2, c0 = (lane & 3) * 16;
#pragma unroll
  for (int mt = 0; mt < 4; ++mt) {
#pragma unroll
    for (int nt = 0; nt < 4; ++nt)
#pragma unroll
      for (int r = 0; r < 4; ++r)
        epsw[(q * 4 + r) * 68 + nt * 16 + mr] = acc[mt][nt][r];
    float v[16];
#pragma unroll
    for (int j = 0; j < 4; ++j) {
      float4 t = *(const float4*)&epsw[rr * 68 + c0 + j * 4];
      v[j * 4 + 0] = t.x; v[j * 4 + 1] = t.y; v[j * 4 + 2] = t.z; v[j * 4 + 3] = t.w;
    }
    const int grow = mblk + wr * 64 + mt * 16 + rr;
    const int gcol = nblk + wc * 64 + c0;

    if constexpr (EPI == 0) {
      int win = grow >> 6, ntok = grow & 63;
      int s = gcol / 384;
      int rem = gcol - s * 384;
      int h = rem >> 5, d0 = rem & 31;
      bf16* op = (bf16*)outp + (((size_t)s * 512 + win) * 12 + h) * 2048 + ntok * 32 + d0;
      uint4 pk;
      float bv[16];
#pragma unroll
      for (int j = 0; j < 16; ++j) bv[j] = v[j] + bias[gcol + j];
      pk.x = pack2(bv[0], bv[1]); pk.y = pack2(bv[2], bv[3]);
      pk.z = pack2(bv[4], bv[5]); pk.w = pack2(bv[6], bv[7]);
      *(uint4*)op = pk;
      pk.x = pack2(bv[8], bv[9]); pk.y = pack2(bv[10], bv[11]);
      pk.z = pack2(bv[12], bv[13]); pk.w = pack2(bv[14], bv[15]);
      *(uint4*)(op + 8) = pk;
    } else if constexpr (EPI == 1) {
      int win = grow >> 6, ntok = grow & 63;
      int bimg = win >> 4, wi = win & 15;
      int hh = (((wi >> 2) << 3) + (ntok >> 3) + 4) & 31;
      int ww = (((wi & 3) << 3) + (ntok & 7) + 4) & 31;
      size_t t = (size_t)bimg * 1024 + hh * 32 + ww;
      bf16* op = (bf16*)outp + t * CDIM + gcol;
      const float* xr = extra + t * CDIM + gcol;
      float ov[16];
#pragma unroll
      for (int j = 0; j < 4; ++j) {
        float4 xv = *(const float4*)(xr + j * 4);
        ov[j * 4 + 0] = xv.x + v[j * 4 + 0] + bias[gcol + j * 4 + 0];
        ov[j * 4 + 1] = xv.y + v[j * 4 + 1] + bias[gcol + j * 4 + 1];
        ov[j * 4 + 2] = xv.z + v[j * 4 + 2] + bias[gcol + j * 4 + 2];
        ov[j * 4 + 3] = xv.w + v[j * 4 + 3] + bias[gcol + j * 4 + 3];
      }
      uint4 pk;
      pk.x = pack2(ov[0], ov[1]); pk.y = pack2(ov[2], ov[3]);
      pk.z = pack2(ov[4], ov[5]); pk.w = pack2(ov[6], ov[7]);
      *(uint4*)op = pk;
      pk.x = pack2(ov[8], ov[9]); pk.y = pack2(ov[10], ov[11]);
      pk.z = pack2(ov[12], ov[13]); pk.w = pack2(ov[14], ov[15]);
      *(uint4*)(op + 8) = pk;
    }
  }
}

// ===================== fused MLP: x1 + fc2(gelu(fc1(ln2))) ==================
// round-5 proven config (124 us, VGPR 120, no spill); x1 now bf16.
__global__ __launch_bounds__(512, 2) void k_mlp(const bf16* __restrict__ A,
                                                const bf16* __restrict__ W1t,
                                                const bf16* __restrict__ W2t,
                                                const float* __restrict__ b1,
                                                const float* __restrict__ b2,
                                                const bf16* __restrict__ x1,
                                                float* __restrict__ out) {
  __shared__ __attribute__((aligned(16))) char pool[131072];
  bf16* A0 = (bf16*)pool;
  bf16* A1 = (bf16*)(pool + 8192);
  bf16* A2 = (bf16*)(pool + 16384);
  bf16* W10 = (bf16*)(pool + 24576);
  bf16* W11 = (bf16*)(pool + 32768);
  bf16* W12 = (bf16*)(pool + 40960);
  bf16* hs = (bf16*)(pool + 49152);     // [128 tok][16 slots][8], XOR layout
  bf16* W2sA = (bf16*)(pool + 81920);   // [192 rowpair][64] = 24 KiB
  bf16* W2sB = (bf16*)(pool + 106496);  // [192 rowpair][64] = 24 KiB

  const int tid = threadIdx.x;
  const int wv = tid >> 6, lane = tid & 63;
  const int mblk = blockIdx.x * 128;

  const int srow = lane >> 3;
  const int sc = (lane & 7) ^ srow;
  const int srow2 = 2 * srow + (sc >> 2);
  const int gco = (sc & 3) * 8;

  const bf16* ga = A + (size_t)(mblk + wv * 16 + srow2) * 384 + gco;
  const bf16* g1 = W1t + (size_t)(wv * 16 + srow2) * 384 + gco;
  const bf16* g2 = W2t + (size_t)(wv * 48 + srow2) * 1536 + gco;

  const int wr1 = wv >> 2, wc1 = wv & 3;
  const int mr = lane & 15, q = lane >> 4;
  const int slot8 = ((((mr & 1) << 2) | q) ^ (mr >> 1)) * 8;
  const int faOff1 = (wr1 * 32 + (mr >> 1)) * 64 + slot8;
  const int fbOff1 = (wc1 * 16 + (mr >> 1)) * 64 + slot8;
  const int fbOff2 = (wc1 * 48 + (mr >> 1)) * 64 + slot8;
  const size_t hb = (size_t)(wr1 * 64 + mr) * 128;
  int px[4];
#pragma unroll
  for (int kk = 0; kk < 4; ++kk)
    px[kk] = (((kk & 2) << 2) | ((((kk & 1) << 2) | q) ^ (mr & 7))) * 8;

  floatx4 acc1[4][2];
  floatx4 acc2[4][6];
#pragma unroll
  for (int i = 0; i < 4; ++i) {
#pragma unroll
    for (int j = 0; j < 2; ++j) acc1[i][j] = floatx4{0.f, 0.f, 0.f, 0.f};
#pragma unroll
    for (int j = 0; j < 6; ++j) acc2[i][j] = floatx4{0.f, 0.f, 0.f, 0.f};
  }

#define VMW(N) asm volatile("s_waitcnt vmcnt(" #N ")" ::: "memory")
#define LGKM0() asm volatile("s_waitcnt lgkmcnt(0)" ::: "memory")
#define BARR() __builtin_amdgcn_s_barrier()
#define ST(ABUF, WBUF, G1P, KO) do { \
    gload16(ga + (KO), (ABUF) + wv * 512); \
    gload16((G1P) + (KO), (WBUF) + wv * 512); \
  } while (0)
#define STW2(BUF, KK) do { \
    _Pragma("unroll") \
    for (int g = 0; g < 3; ++g) \
      gload16(g2 + (KK) * 32 + (size_t)g * 16 * 1536, (BUF) + wv * 1536 + g * 512); \
  } while (0)
#define C1(AB, WB) do { \
    short8 a_[4], b_[2]; \
    _Pragma("unroll") \
    for (int mt = 0; mt < 4; ++mt) a_[mt] = *(const short8*)((AB) + faOff1 + mt * 512); \
    b_[0] = *(const short8*)((WB) + fbOff1); \
    b_[1] = *(const short8*)((WB) + fbOff1 + 512); \
    _Pragma("unroll") \
    for (int mt = 0; mt < 4; ++mt) \
      _Pragma("unroll") \
      for (int nt = 0; nt < 2; ++nt) \
        acc1[mt][nt] = __builtin_amdgcn_mfma_f32_16x16x32_bf16(a_[mt], b_[nt], acc1[mt][nt], 0, 0, 0); \
  } while (0)
#define C2(BUF, KK) do { \
    short8 ha[4], wb[6]; \
    _Pragma("unroll") \
    for (int mt = 0; mt < 4; ++mt) \
      ha[mt] = *(const short8*)(hs + hb + mt * 2048 + px[KK]); \
    _Pragma("unroll") \
    for (int nt = 0; nt < 6; ++nt) \
      wb[nt] = *(const short8*)((BUF) + fbOff2 + nt * 512); \
    _Pragma("unroll") \
    for (int mt = 0; mt < 4; ++mt) \
      _Pragma("unroll") \
      for (int nt = 0; nt < 6; ++nt) \
        acc2[mt][nt] = __builtin_amdgcn_mfma_f32_16x16x32_bf16(ha[mt], wb[nt], acc2[mt][nt], 0, 0, 0); \
  } while (0)
// GELU + bias -> h (XOR layout), rezero acc1
#define GELU_H(BB0, BB1) do { \
    _Pragma("unroll") \
    for (int mt = 0; mt < 4; ++mt) { \
      const int tokb = wr1 * 64 + mt * 16 + q * 4; \
      _Pragma("unroll") \
      for (int nt = 0; nt < 2; ++nt) { \
        const float bb = nt ? (BB1) : (BB0); \
        const int sw = wc1 * 4 + nt * 2 + (mr >> 3); \
        const int s8 = sw & 8, s7 = sw & 7; \
        _Pragma("unroll") \
        for (int r = 0; r < 4; ++r) { \
          float z = acc1[mt][nt][r] + bb; \
          float t2 = z * z; \
          float cp = __builtin_fmaf(t2, -0.0713548162f, -1.5957691216f); \
          float e = __expf(z * cp); \
          float gl = z * __builtin_amdgcn_rcpf(1.f + e); \
          const int t7 = ((q & 1) << 2) | r; \
          hs[(size_t)(tokb + r) * 128 + (s8 | (s7 ^ t7)) * 8 + (mr & 7)] = f2bf(gl); \
        } \
        acc1[mt][nt] = floatx4{0.f, 0.f, 0.f, 0.f}; \
      } \
    } \
    LGKM0(); \
  } while (0)

  // prologue: stages for steps 0,1 of chunk 0
  ST(A0, W10, g1, 0);
  ST(A1, W11, g1, 32);

  for (int ci = 0; ci < 12; ++ci) {
    BARR();  // prev GEMM2 reads of hs/W2sA/W2sB all complete
    const int cb = ci * 128;
    float bb0 = b1[cb + wc1 * 32 + mr];
    float bb1 = b1[cb + wc1 * 32 + 16 + mr];
    STW2(W2sA, 0);  // slice0: 3 gloads, drained by step2's vmcnt(2)

    const bf16* g1n = g1 + 49152;
    VMW(5); BARR(); ST(A2, W12, g1, 64);   C1(A0, W10);
    VMW(5); BARR(); ST(A0, W10, g1, 96);   C1(A1, W11);
    VMW(2); BARR(); ST(A1, W11, g1, 128);  C1(A2, W12);
    VMW(2); BARR(); ST(A2, W12, g1, 160);  C1(A0, W10);
    VMW(2); BARR(); ST(A0, W10, g1, 192);  C1(A1, W11);
    VMW(2); BARR(); ST(A1, W11, g1, 224);  C1(A2, W12);
    VMW(2); BARR(); ST(A2, W12, g1, 256);  C1(A0, W10);
    VMW(2); BARR(); ST(A0, W10, g1, 288);  C1(A1, W11);
    VMW(2); BARR(); ST(A1, W11, g1, 320);  C1(A2, W12);
    VMW(2); BARR(); ST(A2, W12, g1, 352);  C1(A0, W10);
    VMW(2); BARR(); ST(A0, W10, g1n, 0);   C1(A1, W11);
    VMW(2); BARR(); ST(A1, W11, g1n, 32);  C1(A2, W12);

    GELU_H(bb0, bb1);
    __syncthreads();

    // ---- GEMM2: 4 slices, W2sA/W2sB ping-pong, counted vmcnt ----
    STW2(W2sB, 1);
    C2(W2sA, 0);            // slice0 drained at step2 + barriers since
    BARR();                 // all waves done reading W2sA
    STW2(W2sA, 2);
    VMW(3); BARR();         // slice1 complete (leaves slice2 in flight)
    C2(W2sB, 1);
    BARR();                 // all waves done reading W2sB
    STW2(W2sB, 3);
    VMW(3); BARR();         // slice2 complete (leaves slice3 in flight)
    C2(W2sA, 2);
    VMW(0); BARR();         // slice3 complete
    C2(W2sB, 3);

    g1 += 49152;
    g2 += 128;
  }
#undef ST
#undef STW2
#undef C1
#undef C2
#undef GELU_H

  VMW(0);           // drain stray last-chunk prefetches
  __syncthreads();  // before epsw aliases the A/W1/h region

  // ---- epilogue: out = x1(bf16) + acc2 + b2 ----
  float* epsw = (float*)(pool + wv * 6400);  // [16][100] f32 per wave
  const int rr = lane >> 2, c4 = (lane & 3) * 24;
#pragma unroll
  for (int mt = 0; mt < 4; ++mt) {
#pragma unroll
    for (int nt = 0; nt < 6; ++nt)
#pragma unroll
      for (int r = 0; r < 4; ++r)
        epsw[(q * 4 + r) * 100 + nt * 16 + mr] = acc2[mt][nt][r];
    const int grow = mblk + wr1 * 64 + mt * 16 + rr;
    const int gcol = wc1 * 96 + c4;
    const bf16* xr = x1 + (size_t)grow * 384 + gcol;
    float* op = out + (size_t)grow * 384 + gcol;
    float xv[24];
#pragma unroll
    for (int j3 = 0; j3 < 3; ++j3) {
      uint4 xp = *(const uint4*)(xr + j3 * 8);
      xv[j3 * 8 + 0] = bfl(xp.x); xv[j3 * 8 + 1] = bfh(xp.x);
      xv[j3 * 8 + 2] = bfl(xp.y); xv[j3 * 8 + 3] = bfh(xp.y);
      xv[j3 * 8 + 4] = bfl(xp.z); xv[j3 * 8 + 5] = bfh(xp.z);
      xv[j3 * 8 + 6] = bfl(xp.w); xv[j3 * 8 + 7] = bfh(xp.w);
    }
#pragma unroll
    for (int j = 0; j < 6; ++j) {
      float4 t = *(const float4*)&epsw[rr * 100 + c4 + j * 4];
      float4 bv = *(const float4*)&b2[gcol + j * 4];
      float4 ov;
      ov.x = xv[j * 4 + 0] + t.x + bv.x;
      ov.y = xv[j * 4 + 1] + t.y + bv.y;
      ov.z = xv[j * 4 + 2] + t.z + bv.z;
      ov.w = xv[j * 4 + 3] + t.w + bv.w;
      *(float4*)(op + j * 4) = ov;
    }
  }
#undef VMW
#undef LGKM0
#undef BARR
}

// ============ attention on MFMA: 1 wave per (window, head) ==================
__global__ __launch_bounds__(64) void k_attn(const bf16* __restrict__ qkv,
                                             const float* __restrict__ tblg,
                                             bf16* __restrict__ out) {
  __shared__ __attribute__((aligned(16))) char pool[16384];
  bf16* Qs = (bf16*)pool;                                   // [64][40]
  bf16* Ks = (bf16*)(pool + 5120);                          // [64][40]
  bf16* Ps = (bf16*)pool;                                   // [64][72] alias
  float* Os = (float*)pool;                                 // [64][40] alias
  bf16* Vt = (bf16*)(pool + 10240);                         // [32][72]
  unsigned long long* msk = (unsigned long long*)(pool + 14848);  // [64]
  float* tbl = (float*)(pool + 15360);                      // [225]

  const int bid = blockIdx.x;
  const int win = bid / 12, head = bid - win * 12;
  const int lane = threadIdx.x;
  const int q = lane >> 4, mr = lane & 15;

  for (int i = lane; i < 225; i += 64) tbl[i] = tblg[i * 12 + head];

  size_t base = ((size_t)win * 12 + head) * 2048 + lane * 32;
  const uint4* qp = (const uint4*)(qkv + base);
  const uint4* kp = (const uint4*)(qkv + (size_t)12582912 + base);
  const uint4* vp = (const uint4*)(qkv + (size_t)25165824 + base);
#pragma unroll
  for (int i = 0; i < 4; ++i) *(uint4*)(Qs + lane * 40 + i * 8) = qp[i];
#pragma unroll
  for (int i = 0; i < 4; ++i) *(uint4*)(Ks + lane * 40 + i * 8) = kp[i];
  {
    union { uint4 u[4]; unsigned short h[32]; } vv;
#pragma unroll
    for (int i = 0; i < 4; ++i) vv.u[i] = vp[i];
    unsigned short* VtU = (unsigned short*)Vt;
#pragma unroll
    for (int d = 0; d < 32; ++d) VtU[d * 72 + lane] = vv.h[d];
  }
  {
    int wi = win & 15;
    int ri = lane >> 3, ci = lane & 7;
    int rh = ((wi >> 2) << 3) + ri, rw = ((wi & 3) << 3) + ci;
    int rid = (rh < 24 ? 0 : (rh < 28 ? 1 : 2)) * 3 + (rw < 24 ? 0 : (rw < 28 ? 1 : 2));
    unsigned long long m = 0;
#pragma unroll
    for (int v = 0; v < 9; ++v) {
      unsigned long long bb = __ballot(rid == v);
      if (rid == v) m = bb;
    }
    msk[lane] = m;
  }
  // single wave: LDS ops execute in program order, no barrier needed

  // ---- S = Q.K^T ----
  floatx4 sac[4][4];
#pragma unroll
  for (int i = 0; i < 4; ++i)
#pragma unroll
    for (int j = 0; j < 4; ++j) sac[i][j] = floatx4{0.f, 0.f, 0.f, 0.f};
  {
    short8 af[4], bf[4];
#pragma unroll
    for (int t = 0; t < 4; ++t) af[t] = *(const short8*)(Qs + (t * 16 + mr) * 40 + q * 8);
#pragma unroll
    for (int t = 0; t < 4; ++t) bf[t] = *(const short8*)(Ks + (t * 16 + mr) * 40 + q * 8);
#pragma unroll
    for (int mt = 0; mt < 4; ++mt)
#pragma unroll
      for (int nt = 0; nt < 4; ++nt)
        sac[mt][nt] = __builtin_amdgcn_mfma_f32_16x16x32_bf16(af[mt], bf[nt], sac[mt][nt], 0, 0, 0);
  }

  // ---- epilogue: scale + bias + mask + exp; row sums; P -> LDS bf16 ----
  float psum[4][4];
#pragma unroll
  for (int mt = 0; mt < 4; ++mt)
#pragma unroll
    for (int r = 0; r < 4; ++r) psum[mt][r] = 0.f;
#pragma unroll
  for (int mt = 0; mt < 4; ++mt) {
#pragma unroll
    for (int r = 0; r < 4; ++r) {
      const int i = mt * 16 + q * 4 + r;
      const unsigned long long mrow = msk[i];
      const int bi = (i >> 3) * 15 + (i & 7);
#pragma unroll
      for (int nt = 0; nt < 4; ++nt) {
        const int j = nt * 16 + mr;
        const int idx = bi + 112 - (j >> 3) * 15 - (j & 7);
        float val = sac[mt][nt][r] * 0.17677669529663687f + tbl[idx];
        float p = __expf(val);
        p = ((mrow >> j) & 1ull) ? p : 0.f;
        psum[mt][r] += p;
        Ps[i * 72 + j] = f2bf(p);
      }
    }
  }
  float inv[4][4];
#pragma unroll
  for (int mt = 0; mt < 4; ++mt)
#pragma unroll
    for (int r = 0; r < 4; ++r) {
      float s = psum[mt][r];
      s += __shfl_xor(s, 1, 64);
      s += __shfl_xor(s, 2, 64);
      s += __shfl_xor(s, 4, 64);
      s += __shfl_xor(s, 8, 64);
      inv[mt][r] = 1.f / s;
    }

  // ---- O = P.V ----
  floatx4 oac[4][2];
#pragma unroll
  for (int i = 0; i < 4; ++i)
#pragma unroll
    for (int j = 0; j < 2; ++j) oac[i][j] = floatx4{0.f, 0.f, 0.f, 0.f};
#pragma unroll
  for (int kk = 0; kk < 2; ++kk) {
    short8 ap[4], bv[2];
#pragma unroll
    for (int mt = 0; mt < 4; ++mt)
      ap[mt] = *(const short8*)(Ps + (mt * 16 + mr) * 72 + kk * 32 + q * 8);
#pragma unroll
    for (int nt = 0; nt < 2; ++nt)
      bv[nt] = *(const short8*)(Vt + (nt * 16 + mr) * 72 + kk * 32 + q * 8);
#pragma unroll
    for (int mt = 0; mt < 4; ++mt)
#pragma unroll
      for (int nt = 0; nt < 2; ++nt)
        oac[mt][nt] = __builtin_amdgcn_mfma_f32_16x16x32_bf16(ap[mt], bv[nt], oac[mt][nt], 0, 0, 0);
  }

  // ---- normalize + LDS round-trip -> vectorized store ----
#pragma unroll
  for (int mt = 0; mt < 4; ++mt)
#pragma unroll
    for (int nt = 0; nt < 2; ++nt)
#pragma unroll
      for (int r = 0; r < 4; ++r)
        Os[(mt * 16 + q * 4 + r) * 40 + nt * 16 + mr] = oac[mt][nt][r] * inv[mt][r];
  float ov[32];
#pragma unroll
  for (int c = 0; c < 8; ++c) {
    const int cc = c ^ (lane & 7);
    float4 t = *(const float4*)(Os + lane * 40 + cc * 4);
    ov[cc * 4 + 0] = t.x; ov[cc * 4 + 1] = t.y;
    ov[cc * 4 + 2] = t.z; ov[cc * 4 + 3] = t.w;
  }
  uint4* o4 = (uint4*)(out + ((size_t)win * 64 + lane) * CDIM + head * 32);
#pragma unroll
  for (int i = 0; i < 4; ++i) {
    uint4 pk;
    pk.x = pack2(ov[i * 8 + 0], ov[i * 8 + 1]);
    pk.y = pack2(ov[i * 8 + 2], ov[i * 8 + 3]);
    pk.z = pack2(ov[i * 8 + 4], ov[i * 8 + 5]);
    pk.w = pack2(ov[i * 8 + 6], ov[i * 8 + 7]);
    o4[i] = pk;
  }
}

extern "C" void kernel_launch(void* const* d_in, const int* in_sizes, int n_in,
                              void* d_out, int out_size, void* d_ws, size_t ws_size,
                              hipStream_t stream) {
  const float* x = (const float*)d_in[0];
  const float* n1g = (const float*)d_in[1];
  const float* n1b = (const float*)d_in[2];
  const float* qkv_w = (const float*)d_in[3];
  const float* qkv_b = (const float*)d_in[4];
  const float* reltbl = (const float*)d_in[5];
  const float* proj_w = (const float*)d_in[6];
  const float* proj_b = (const float*)d_in[7];
  const float* n2g = (const float*)d_in[8];
  const float* n2b = (const float*)d_in[9];
  const float* fc1_w = (const float*)d_in[10];
  const float* fc1_b = (const float*)d_in[11];
  const float* fc2_w = (const float*)d_in[12];
  const float* fc2_b = (const float*)d_in[13];
  float* out = (float*)d_out;

  char* p = (char*)d_ws;
  bf16* w_qkv_t = (bf16*)p;  p += (size_t)442368 * 2;
  bf16* w_proj_t = (bf16*)p; p += (size_t)147456 * 2;
  bf16* w_fc1_t = (bf16*)p;  p += (size_t)589824 * 2;
  bf16* w_fc2_t = (bf16*)p;  p += (size_t)589824 * 2;
  bf16* bufA = (bf16*)p;     p += (size_t)12582912 * 2;
  bf16* qkvb = (bf16*)p;     p += (size_t)37748736 * 2;
  bf16* attno = (bf16*)p;    p += (size_t)12582912 * 2;
  bf16* x1 = (bf16*)p;       p += (size_t)12582912 * 2;

  k_pre<<<dim3(15104), dim3(256), 0, stream>>>(qkv_w, w_qkv_t, proj_w, w_proj_t,
                                               fc1_w, w_fc1_t, fc2_w, w_fc2_t,
                                               x, n1g, n1b, bufA);

  k_gemm<384, 0, 9><<<dim3(9 * 256), dim3(256), 0, stream>>>(bufA, w_qkv_t, qkv_b, nullptr, qkvb);
  k_attn<<<dim3(6144), dim3(64), 0, stream>>>(qkvb, reltbl, attno);
  k_gemm<384, 1, 3><<<dim3(3 * 256), dim3(256), 0, stream>>>(attno, w_proj_t, proj_b, x, x1);
  k_ln2<<<dim3(8192), dim3(256), 0, stream>>>(x1, n2g, n2b, bufA);
  k_mlp<<<dim3(256), dim3(512), 0, stream>>>(bufA, w_fc1_t, w_fc2_t, fc1_b, fc2_b, x1, out);
}